// Round 11
// baseline (615.503 us; speedup 1.0000x reference)
//
#include <hip/hip_runtime.h>
#include <hip/hip_bf16.h>
#include <cmath>

typedef unsigned short u16;
typedef __attribute__((ext_vector_type(4))) float f32x4;
typedef __attribute__((ext_vector_type(8))) short s16x8;

__device__ __forceinline__ float b2f(u16 u) { return __uint_as_float(((unsigned)u) << 16); }
__device__ __forceinline__ u16 f2b(float f) {
    unsigned u = __float_as_uint(f);
    unsigned r = (u + 0x7fffu + ((u >> 16) & 1u)) >> 16;
    return (u16)r;
}
// tanh-based gelu: |err| < ~1e-3 for our |x|<1.5 -- within bf16 tolerance
__device__ __forceinline__ float gelu_f(float x) {
    float t = x * (0.7978845608f + 0.0356774081f * x * x);
    float e = exp2f(2.885390082f * t);
    return 0.5f * x * (1.0f + (e - 1.0f) / (e + 1.0f));
}

#define FOLD 0.25503590f   // (1/sqrt(32)) * log2(e)

// ---------------- prep0: cast weights to bf16 ----------------
__global__ __launch_bounds__(256) void prep0_k(const float* __restrict__ pw_w,
        const float* __restrict__ lg_Wq, const float* __restrict__ lg_Wo,
        const float* __restrict__ dec_Wk, const float* __restrict__ dec_Wv,
        const float* __restrict__ dec_Wo, const float* __restrict__ ff1_w,
        const float* __restrict__ ff2_w,
        u16* __restrict__ pwb, u16* __restrict__ Wq_b, u16* __restrict__ Wo_b,
        u16* __restrict__ Wk2_b, u16* __restrict__ Wv2_b, u16* __restrict__ Wo2b,
        u16* __restrict__ ff1b, u16* __restrict__ ff2b)
{
    int idx = blockIdx.x * 256 + threadIdx.x;     // 598016 total
    if (idx < 327680) {
        int which = idx >> 16, r = idx & 65535;
        const float* srcs[5] = {lg_Wq, lg_Wo, dec_Wk, dec_Wv, dec_Wo};
        u16* dsts[5] = {Wq_b, Wo_b, Wk2_b, Wv2_b, Wo2b};
        dsts[which][r] = f2b(srcs[which][r]);
    } else if (idx < 458752) {
        int r = idx - 327680;
        ff1b[r] = f2b(ff1_w[r]);
    } else if (idx < 589824) {
        int r = idx - 458752;
        ff2b[r] = f2b(ff2_w[r]);
    } else {
        int r = idx - 589824;
        pwb[r] = f2b(pw_w[r]);
    }
}

// ---------------- fused frontend: depthwise + pointwise MFMA + gelu + stat sums ----------------
__global__ __launch_bounds__(256) void dwpw_k(const float* __restrict__ x,
        const float* __restrict__ dw_w, const u16* __restrict__ pwb,
        u16* __restrict__ zp, float* __restrict__ csum, float* __restrict__ csum2)
{
    __shared__ float xs[68][33];
    __shared__ __align__(16) u16 As[64][40];
    const int t = threadIdx.x;
    const int b = blockIdx.x >> 6, s0 = (blockIdx.x & 63) << 6;
    const int r0 = blockIdx.x * 64;
    const int lane = t & 63, w = t >> 6;
    const int l16 = lane & 15, hi = lane >> 4;

    for (int idx = t; idx < 68 * 32; idx += 256) {
        int row = idx >> 5, c = idx & 31;
        int sg = s0 - 2 + row;
        xs[row][c] = (sg >= 0 && sg < 4096) ? x[((size_t)b * 4096 + sg) * 32 + c] : 0.0f;
    }
    const int cc = t & 31;
    float wv[5];
    #pragma unroll
    for (int k = 0; k < 5; ++k) wv[k] = dw_w[cc * 5 + k];
    __syncthreads();
    #pragma unroll
    for (int i = 0; i < 8; ++i) {
        int sl = (t + i * 256) >> 5;
        float acc = 0;
        #pragma unroll
        for (int k = 0; k < 5; ++k) acc += xs[sl + k][cc] * wv[k];
        As[sl][cc] = f2b(acc);
    }
    __syncthreads();

    const int n0 = w * 64;
    f32x4 zero = {0, 0, 0, 0};
    s16x8 bf[4];
    #pragma unroll
    for (int ni = 0; ni < 4; ++ni)
        bf[ni] = *(const s16x8*)(pwb + (n0 + ni * 16 + l16) * 32 + hi * 8);

    float cl[4] = {0,0,0,0}, ch[4] = {0,0,0,0};
    float ql[4] = {0,0,0,0}, qh[4] = {0,0,0,0};

    #pragma unroll
    for (int mi = 0; mi < 4; ++mi) {
        s16x8 af = *(const s16x8*)&As[mi * 16 + l16][hi * 8];
        #pragma unroll
        for (int ni = 0; ni < 4; ++ni) {
            f32x4 acc = __builtin_amdgcn_mfma_f32_16x16x32_bf16(af, bf[ni], zero, 0, 0, 0);
            int col = n0 + ni * 16 + l16;
            int rowb = r0 + mi * 16 + hi * 4;
            #pragma unroll
            for (int r = 0; r < 4; ++r) {
                float e = gelu_f(acc[r]);
                zp[(size_t)(rowb + r) * 256 + col] = f2b(e);
                if (mi < 2) { cl[ni] += e; ql[ni] += e * e; }
                else        { ch[ni] += e; qh[ni] += e * e; }
            }
        }
    }
    #pragma unroll
    for (int ni = 0; ni < 4; ++ni) {
        #pragma unroll
        for (int m = 16; m <= 32; m <<= 1) {
            cl[ni] += __shfl_xor(cl[ni], m);
            ch[ni] += __shfl_xor(ch[ni], m);
            ql[ni] += __shfl_xor(ql[ni], m);
            qh[ni] += __shfl_xor(qh[ni], m);
        }
        if (lane < 16) {
            int col = n0 + ni * 16 + lane;
            size_t bc = (size_t)(r0 >> 5);
            csum [bc * 256 + col]       = cl[ni];
            csum [(bc + 1) * 256 + col] = ch[ni];
            csum2[bc * 256 + col]       = ql[ni];
            csum2[(bc + 1) * 256 + col] = qh[ni];
        }
    }
}

// ---------------- stats2 ----------------
__global__ __launch_bounds__(256) void stats2_k(const float* __restrict__ csum,
        const float* __restrict__ csum2, float* __restrict__ statp)
{
    int j = blockIdx.x, t = threadIdx.x;
    float s1 = 0, s2 = 0;
    for (int i = 0; i < 64; ++i) {
        s1 += csum [(size_t)(j * 64 + i) * 256 + t];
        s2 += csum2[(size_t)(j * 64 + i) * 256 + t];
    }
    statp[j * 512 + t] = s1;
    statp[j * 512 + 256 + t] = s2;
}

// ---------------- prep1: BN affine + gate coef ----------------
__global__ __launch_bounds__(256) void prep1_k(const float* __restrict__ statp,
        const float* __restrict__ bn_g, const float* __restrict__ bn_b,
        const float* __restrict__ gate_logits,
        float* __restrict__ a_ws, float* __restrict__ c_ws, float* __restrict__ coef)
{
    int t = threadIdx.x;
    float s1 = 0, s2 = 0;
    for (int j = 0; j < 64; ++j) {
        s1 += statp[j * 512 + t];
        s2 += statp[j * 512 + 256 + t];
    }
    const float invN = 1.0f / 131072.0f;
    float mean = s1 * invN;
    float var = s2 * invN - mean * mean;
    float av = bn_g[t] * rsqrtf(var + 1e-5f);
    a_ws[t] = av;
    c_ws[t] = bn_b[t] - mean * av;
    if (t < 24) {
        float g0 = gate_logits[t * 3], g1 = gate_logits[t * 3 + 1], g2 = gate_logits[t * 3 + 2];
        float mx = fmaxf(g0, fmaxf(g1, g2));
        float e0 = __expf(g0 - mx), e1 = __expf(g1 - mx), e2 = __expf(g2 - mx);
        coef[t] = (e1 + e2) / (e0 + e1 + e2);
    }
}

// ---------------- prepx: prep2b (512) + q2 (16) + qgemm (64) in one dispatch ----------------
__global__ __launch_bounds__(256) void prepx_k(const float* __restrict__ lg_Wk,
        const float* __restrict__ lg_Wv, const float* __restrict__ a_ws,
        const float* __restrict__ c_ws, const float* __restrict__ dec_Qd,
        const float* __restrict__ dec_Wq, const float* __restrict__ csum,
        const u16* __restrict__ Wq_b,
        u16* __restrict__ Wk_b, u16* __restrict__ Wv_b,
        float* __restrict__ betak, float* __restrict__ betav,
        float* __restrict__ q2, u16* __restrict__ qb)
{
    __shared__ __align__(16) char sm[41728];
    const int bid = blockIdx.x, t = threadIdx.x;
    if (bid < 512) {
        float* red = (float*)sm;
        int which = bid >> 8, row = bid & 255;
        const float* Wsrc = which ? lg_Wv : lg_Wk;
        float wv = Wsrc[row * 256 + t];
        (which ? Wv_b : Wk_b)[row * 256 + t] = f2b(wv * a_ws[t]);
        float v = wv * c_ws[t];
        for (int m = 32; m; m >>= 1) v += __shfl_xor(v, m);
        if ((t & 63) == 0) red[t >> 6] = v;
        __syncthreads();
        if (t == 0) (which ? betav : betak)[row] = red[0] + red[1] + red[2] + red[3];
    } else if (bid < 528) {
        float (*wq)[260] = (float(*)[260])sm;
        float (*qd)[260] = (float(*)[260])(sm + 16640);
        int j = bid - 512;
        for (int idx = t; idx < 4096; idx += 256) {
            int tl = idx >> 8, d = idx & 255;
            wq[tl][d] = dec_Wq[(j * 16 + tl) * 256 + d];
        }
        for (int idx = t; idx < 6144; idx += 256) {
            int p = idx >> 8, d = idx & 255;
            qd[p][d] = dec_Qd[idx];
        }
        __syncthreads();
        for (int o = t; o < 384; o += 256) {
            int p = o >> 4, tl = o & 15;
            float s = 0;
            #pragma unroll 8
            for (int d = 0; d < 256; ++d) s += qd[p][d] * wq[tl][d];
            q2[p * 256 + j * 16 + tl] = s;
        }
    } else {
        u16* As = (u16*)sm;                       // 32KB
        float* aa = (float*)(sm + 32768);
        float* ccx = (float*)(sm + 33792);
        const int r0 = (bid - 528) * 64;
        const int lane = t & 63, w = t >> 6;
        const int l16 = lane & 15, hi = lane >> 4;
        aa[t] = a_ws[t] * 0.015625f;
        ccx[t] = c_ws[t];
        __syncthreads();
        #pragma unroll
        for (int i = 0; i < 8; ++i) {
            int c = t + i * 256;
            int row = c >> 5, c16 = c & 31;
            int g = r0 + row, mm = g & 127;
            u16 tmp[8];
            if (mm == 127) {
                #pragma unroll
                for (int j = 0; j < 8; ++j) tmp[j] = 0;
            } else {
                const float* c0p = csum + (size_t)g * 256 + c16 * 8;
                const float* c1p = c0p + 256;
                #pragma unroll
                for (int j = 0; j < 8; ++j) {
                    int d = c16 * 8 + j;
                    tmp[j] = f2b((c0p[j] + c1p[j]) * aa[d] + ccx[d]);
                }
            }
            int boff = (c16 * 16) ^ ((row & 7) << 4);
            *(s16x8*)((char*)As + row * 512 + boff) = *(s16x8*)tmp;
        }
        __syncthreads();
        const int n0 = w * 64;
        f32x4 zero = {0, 0, 0, 0};
        f32x4 acc[4][4];
        #pragma unroll
        for (int mi = 0; mi < 4; ++mi)
            #pragma unroll
            for (int ni = 0; ni < 4; ++ni) acc[mi][ni] = zero;
        #pragma unroll
        for (int kk = 0; kk < 8; ++kk) {
            s16x8 af[4], bf[4];
            #pragma unroll
            for (int mi = 0; mi < 4; ++mi) {
                int row = mi * 16 + l16;
                int boff = (kk * 64 + hi * 16) ^ ((row & 7) << 4);
                af[mi] = *(const s16x8*)((const char*)As + row * 512 + boff);
            }
            #pragma unroll
            for (int ni = 0; ni < 4; ++ni)
                bf[ni] = *(const s16x8*)(Wq_b + (n0 + ni * 16 + l16) * 256 + kk * 32 + hi * 8);
            #pragma unroll
            for (int mi = 0; mi < 4; ++mi)
                #pragma unroll
                for (int ni = 0; ni < 4; ++ni)
                    acc[mi][ni] = __builtin_amdgcn_mfma_f32_16x16x32_bf16(af[mi], bf[ni], acc[mi][ni], 0, 0, 0);
        }
        #pragma unroll
        for (int mi = 0; mi < 4; ++mi)
            #pragma unroll
            for (int ni = 0; ni < 4; ++ni) {
                int col = n0 + ni * 16 + l16;
                int rowb = r0 + mi * 16 + hi * 4;
                #pragma unroll
                for (int r = 0; r < 4; ++r)
                    qb[(size_t)(rowb + r) * 256 + col] = f2b(acc[mi][ni][r] * FOLD);
            }
    }
}

// ---------------- fused K/V projection: kb row-major + vT blocked-transposed ----------------
// vT layout: [b*8+h][sblk(64)][dh(32)][sl(64)]
__global__ __launch_bounds__(256) void kv_k(const u16* __restrict__ zp,
        const u16* __restrict__ Wk, const u16* __restrict__ Wv,
        const float* __restrict__ betak, const float* __restrict__ betav,
        u16* __restrict__ kb, u16* __restrict__ vT)
{
    __shared__ __align__(16) char smem[36864];
    const int t = threadIdx.x;
    const int r0 = blockIdx.x * 64;
    const int lane = t & 63, w = t >> 6;
    const int l16 = lane & 15, hi = lane >> 4;

    const u16* Ag = zp + (size_t)r0 * 256;
    #pragma unroll
    for (int i = 0; i < 8; ++i) {
        int c = t + i * 256;
        int row = c >> 5, c16 = c & 31;
        s16x8 v = *(const s16x8*)(Ag + row * 256 + c16 * 8);
        int boff = (c16 * 16) ^ ((row & 7) << 4);
        *(s16x8*)(smem + row * 512 + boff) = v;
    }
    __syncthreads();

    const int n0 = w * 64;
    f32x4 zero = {0, 0, 0, 0};
    f32x4 acc[4][4];
    #pragma unroll
    for (int mi = 0; mi < 4; ++mi)
        #pragma unroll
        for (int ni = 0; ni < 4; ++ni) acc[mi][ni] = zero;

    #pragma unroll
    for (int kk = 0; kk < 8; ++kk) {
        s16x8 af[4], bfk[4];
        #pragma unroll
        for (int mi = 0; mi < 4; ++mi) {
            int row = mi * 16 + l16;
            int boff = (kk * 64 + hi * 16) ^ ((row & 7) << 4);
            af[mi] = *(const s16x8*)(smem + row * 512 + boff);
        }
        #pragma unroll
        for (int ni = 0; ni < 4; ++ni)
            bfk[ni] = *(const s16x8*)(Wk + (n0 + ni * 16 + l16) * 256 + kk * 32 + hi * 8);
        #pragma unroll
        for (int mi = 0; mi < 4; ++mi)
            #pragma unroll
            for (int ni = 0; ni < 4; ++ni)
                acc[mi][ni] = __builtin_amdgcn_mfma_f32_16x16x32_bf16(af[mi], bfk[ni], acc[mi][ni], 0, 0, 0);
    }
    #pragma unroll
    for (int mi = 0; mi < 4; ++mi)
        #pragma unroll
        for (int ni = 0; ni < 4; ++ni) {
            int col = n0 + ni * 16 + l16;
            float bv = betak[col];
            int rowb = r0 + mi * 16 + hi * 4;
            #pragma unroll
            for (int r = 0; r < 4; ++r)
                kb[(size_t)(rowb + r) * 256 + col] = f2b(acc[mi][ni][r] + bv);
        }

    #pragma unroll
    for (int mi = 0; mi < 4; ++mi)
        #pragma unroll
        for (int ni = 0; ni < 4; ++ni) acc[mi][ni] = zero;
    #pragma unroll
    for (int kk = 0; kk < 8; ++kk) {
        s16x8 af[4], bfv[4];
        #pragma unroll
        for (int mi = 0; mi < 4; ++mi) {
            int row = mi * 16 + l16;
            int boff = (kk * 64 + hi * 16) ^ ((row & 7) << 4);
            af[mi] = *(const s16x8*)(smem + row * 512 + boff);
        }
        #pragma unroll
        for (int ni = 0; ni < 4; ++ni)
            bfv[ni] = *(const s16x8*)(Wv + (n0 + ni * 16 + l16) * 256 + kk * 32 + hi * 8);
        #pragma unroll
        for (int mi = 0; mi < 4; ++mi)
            #pragma unroll
            for (int ni = 0; ni < 4; ++ni)
                acc[mi][ni] = __builtin_amdgcn_mfma_f32_16x16x32_bf16(af[mi], bfv[ni], acc[mi][ni], 0, 0, 0);
    }
    __syncthreads();
    #pragma unroll
    for (int mi = 0; mi < 4; ++mi)
        #pragma unroll
        for (int ni = 0; ni < 4; ++ni) {
            int col = n0 + ni * 16 + l16;
            float bv = betav[col];
            int rowb = mi * 16 + hi * 4;
            ushort4 pk;
            pk.x = f2b(acc[mi][ni][0] + bv);
            pk.y = f2b(acc[mi][ni][1] + bv);
            pk.z = f2b(acc[mi][ni][2] + bv);
            pk.w = f2b(acc[mi][ni][3] + bv);
            char* p = smem + col * 144 + ((((rowb >> 3) ^ (col & 7)) & 7) << 4) + ((rowb & 7) << 1);
            *(ushort4*)p = pk;
        }
    __syncthreads();
    const int b = r0 >> 12;
    const int sblk = (r0 & 4095) >> 6;
    u16* vout = vT + (size_t)(b * 8) * 131072 + (size_t)sblk * 2048;
    #pragma unroll
    for (int j = 0; j < 8; ++j) {
        int gid = j * 256 + t;
        int col = gid >> 3, oct = gid & 7;
        const char* p = smem + col * 144 + (((oct ^ (col & 7)) & 7) << 4);
        s16x8 v = *(const s16x8*)p;
        int h = col >> 5, dh = col & 31;
        *(s16x8*)(vout + (size_t)h * 131072 + dh * 64 + oct * 8) = v;
    }
}

// ---------------- generic MFMA GEMM (used for ff1 w/ gelu) ----------------
template<int MODE>
__global__ __launch_bounds__(256) void gemm_g(const u16* __restrict__ A,
        const u16* __restrict__ W, const float* __restrict__ bias,
        void* __restrict__ Cout, int K, int ntn)
{
    __shared__ u16 As[64 * 256];
    const int t = threadIdx.x;
    const int rt = blockIdx.x / ntn, nt = blockIdx.x % ntn;
    const int r0 = rt * 64, N = ntn * 256;
    const int lane = t & 63, w = t >> 6;
    const int l16 = lane & 15, hi = lane >> 4;

    const u16* Ag = A + (size_t)r0 * K;
    const int n0 = w * 64;
    f32x4 zero = {0, 0, 0, 0};
    f32x4 acc[4][4];
    #pragma unroll
    for (int mi = 0; mi < 4; ++mi)
        #pragma unroll
        for (int ni = 0; ni < 4; ++ni) acc[mi][ni] = zero;

    for (int kc = 0; kc < K; kc += 256) {
        if (kc) __syncthreads();
        #pragma unroll
        for (int i = 0; i < 8; ++i) {
            int c = t + i * 256;
            int row = c >> 5, c16 = c & 31;
            s16x8 v = *(const s16x8*)(Ag + (size_t)row * K + kc + c16 * 8);
            int boff = (c16 * 16) ^ ((row & 7) << 4);
            *(s16x8*)((char*)As + row * 512 + boff) = v;
        }
        __syncthreads();
        #pragma unroll
        for (int kk = 0; kk < 8; ++kk) {
            s16x8 af[4], bf[4];
            #pragma unroll
            for (int mi = 0; mi < 4; ++mi) {
                int row = mi * 16 + l16;
                int boff = (kk * 64 + hi * 16) ^ ((row & 7) << 4);
                af[mi] = *(const s16x8*)((const char*)As + row * 512 + boff);
            }
            #pragma unroll
            for (int ni = 0; ni < 4; ++ni) {
                int j = nt * 256 + n0 + ni * 16 + l16;
                bf[ni] = *(const s16x8*)(W + (size_t)j * K + kc + kk * 32 + hi * 8);
            }
            #pragma unroll
            for (int mi = 0; mi < 4; ++mi)
                #pragma unroll
                for (int ni = 0; ni < 4; ++ni)
                    acc[mi][ni] = __builtin_amdgcn_mfma_f32_16x16x32_bf16(af[mi], bf[ni], acc[mi][ni], 0, 0, 0);
        }
    }

    #pragma unroll
    for (int mi = 0; mi < 4; ++mi)
        #pragma unroll
        for (int ni = 0; ni < 4; ++ni) {
            int col = nt * 256 + n0 + ni * 16 + l16;
            float bv = bias ? bias[col] : 0.0f;
            int rowb = r0 + mi * 16 + hi * 4;
            #pragma unroll
            for (int r = 0; r < 4; ++r) {
                float v = acc[mi][ni][r] + bv;
                if (MODE == 0)      ((u16*)Cout)[(size_t)(rowb + r) * N + col] = f2b(v);
                else if (MODE == 1) ((float*)Cout)[(size_t)(rowb + r) * N + col] = v;
                else                ((u16*)Cout)[(size_t)(rowb + r) * N + col] = f2b(gelu_f(v));
            }
        }
}

// ---------------- dual 256-K GEMM: Hb -> k2b / v2b ----------------
__global__ __launch_bounds__(256) void gemm_dual(const u16* __restrict__ A,
        const u16* __restrict__ W0, const u16* __restrict__ W1,
        u16* __restrict__ C0, u16* __restrict__ C1)
{
    __shared__ u16 As[64 * 256];
    const int t = threadIdx.x;
    const int which = blockIdx.x >> 6;
    const int r0 = (blockIdx.x & 63) * 64;
    const u16* W = which ? W1 : W0;
    u16* C = which ? C1 : C0;
    const int lane = t & 63, w = t >> 6;
    const int l16 = lane & 15, hi = lane >> 4;

    const u16* Ag = A + (size_t)r0 * 256;
    #pragma unroll
    for (int i = 0; i < 8; ++i) {
        int c = t + i * 256;
        int row = c >> 5, c16 = c & 31;
        s16x8 v = *(const s16x8*)(Ag + row * 256 + c16 * 8);
        int boff = (c16 * 16) ^ ((row & 7) << 4);
        *(s16x8*)((char*)As + row * 512 + boff) = v;
    }
    __syncthreads();

    const int n0 = w * 64;
    f32x4 zero = {0, 0, 0, 0};
    f32x4 acc[4][4];
    #pragma unroll
    for (int mi = 0; mi < 4; ++mi)
        #pragma unroll
        for (int ni = 0; ni < 4; ++ni) acc[mi][ni] = zero;

    #pragma unroll
    for (int kk = 0; kk < 8; ++kk) {
        s16x8 af[4], bf[4];
        #pragma unroll
        for (int mi = 0; mi < 4; ++mi) {
            int row = mi * 16 + l16;
            int boff = (kk * 64 + hi * 16) ^ ((row & 7) << 4);
            af[mi] = *(const s16x8*)((const char*)As + row * 512 + boff);
        }
        #pragma unroll
        for (int ni = 0; ni < 4; ++ni)
            bf[ni] = *(const s16x8*)(W + (n0 + ni * 16 + l16) * 256 + kk * 32 + hi * 8);
        #pragma unroll
        for (int mi = 0; mi < 4; ++mi)
            #pragma unroll
            for (int ni = 0; ni < 4; ++ni)
                acc[mi][ni] = __builtin_amdgcn_mfma_f32_16x16x32_bf16(af[mi], bf[ni], acc[mi][ni], 0, 0, 0);
    }
    #pragma unroll
    for (int mi = 0; mi < 4; ++mi)
        #pragma unroll
        for (int ni = 0; ni < 4; ++ni) {
            int col = n0 + ni * 16 + l16;
            int rowb = r0 + mi * 16 + hi * 4;
            #pragma unroll
            for (int r = 0; r < 4; ++r)
                C[(size_t)(rowb + r) * 256 + col] = f2b(acc[mi][ni][r]);
        }
}

// ---------------- fused attention: 16 waves = 8 q-groups x 2 s-halves ----------------
__global__ __launch_bounds__(1024) void attn_k(const u16* __restrict__ qb,
        const u16* __restrict__ kb, const u16* __restrict__ vT,
        u16* __restrict__ ob, float* __restrict__ attn_out)
{
    __shared__ __align__(16) char sm[36864];
    const int b = blockIdx.x >> 3, h = blockIdx.x & 7;
    const int t = threadIdx.x, w = t >> 6, lane = t & 63;
    const int qg = w >> 1, sh = w & 1;
    const int l16 = lane & 15, hi = lane >> 4;

    u16* p_lds = (u16*)sm + w * 768;          // per-wave [16][48] u16

    s16x8 qf = *(const s16x8*)(qb + ((size_t)(b * 128 + qg * 16 + l16)) * 256 + h * 32 + hi * 8);
    const u16* kbase = kb + (size_t)b * 4096 * 256 + h * 32 + hi * 8;
    const u16* vbase = vT + (size_t)(b * 8 + h) * 131072 + hi * 8;

    float dacc[4] = {0, 0, 0, 0};
    f32x4 zero = {0, 0, 0, 0};
    f32x4 oacc[2]; oacc[0] = zero; oacc[1] = zero;

    const int sbeg = sh * 2048, send = sbeg + 2048;
    s16x8 kf0 = *(const s16x8*)(kbase + (size_t)(sbeg + l16) * 256);
    s16x8 kf1 = *(const s16x8*)(kbase + (size_t)(sbeg + 16 + l16) * 256);
    s16x8 vf0 = *(const s16x8*)(vbase + (sbeg >> 6) * 2048 + l16 * 64 + (sbeg & 63));
    s16x8 vf1 = *(const s16x8*)(vbase + (sbeg >> 6) * 2048 + (16 + l16) * 64 + (sbeg & 63));

    for (int s0 = sbeg; s0 < send; s0 += 32) {
        s16x8 k0 = kf0, k1 = kf1, v0 = vf0, v1 = vf1;
        int sn = s0 + 32;
        if (sn < send) {
            kf0 = *(const s16x8*)(kbase + (size_t)(sn + l16) * 256);
            kf1 = *(const s16x8*)(kbase + (size_t)(sn + 16 + l16) * 256);
            vf0 = *(const s16x8*)(vbase + (sn >> 6) * 2048 + l16 * 64 + (sn & 63));
            vf1 = *(const s16x8*)(vbase + (sn >> 6) * 2048 + (16 + l16) * 64 + (sn & 63));
        }
        f32x4 lg0 = __builtin_amdgcn_mfma_f32_16x16x32_bf16(qf, k0, zero, 0, 0, 0);
        f32x4 lg1 = __builtin_amdgcn_mfma_f32_16x16x32_bf16(qf, k1, zero, 0, 0, 0);
        #pragma unroll
        for (int r = 0; r < 4; ++r) {
            float e0 = exp2f(lg0[r]);
            float e1 = exp2f(lg1[r]);
            dacc[r] += e0 + e1;
            p_lds[(hi * 4 + r) * 48 + l16] = f2b(e0);
            p_lds[(hi * 4 + r) * 48 + 16 + l16] = f2b(e1);
        }
        s16x8 pf = *(const s16x8*)(p_lds + l16 * 48 + hi * 8);
        oacc[0] = __builtin_amdgcn_mfma_f32_16x16x32_bf16(pf, v0, oacc[0], 0, 0, 0);
        oacc[1] = __builtin_amdgcn_mfma_f32_16x16x32_bf16(pf, v1, oacc[1], 0, 0, 0);
    }

    // intra-wave reduce over the 16 s-columns
    #pragma unroll
    for (int m = 1; m <= 8; m <<= 1) {
        #pragma unroll
        for (int r = 0; r < 4; ++r) dacc[r] += __shfl_xor(dacc[r], m);
    }

    // cross-pair reduce (sh=0 <-> sh=1) via LDS
    __syncthreads();                              // all waves done with p_lds
    float* op = (float*)sm;                       // [16][16][32]
    float* den_s = (float*)(sm + 32768);          // [16][16]
    #pragma unroll
    for (int vi = 0; vi < 2; ++vi)
        #pragma unroll
        for (int r = 0; r < 4; ++r)
            op[((w * 16 + hi * 4 + r) * 32) + vi * 16 + l16] = oacc[vi][r];
    if (l16 == 0) {
        #pragma unroll
        for (int r = 0; r < 4; ++r) den_s[w * 16 + hi * 4 + r] = dacc[r];
    }
    __syncthreads();
    float rinv[4];
    #pragma unroll
    for (int r = 0; r < 4; ++r)
        rinv[r] = 1.0f / (dacc[r] + den_s[(w ^ 1) * 16 + hi * 4 + r]);

    if (sh == 0) {
        #pragma unroll
        for (int vi = 0; vi < 2; ++vi)
            #pragma unroll
            for (int r = 0; r < 4; ++r) {
                int mg = qg * 16 + hi * 4 + r;
                float o = oacc[vi][r] + op[(((w ^ 1) * 16 + hi * 4 + r) * 32) + vi * 16 + l16];
                ob[(size_t)(b * 128 + mg) * 256 + h * 32 + vi * 16 + l16] = f2b(o * rinv[r]);
            }
    }
    __syncthreads();                              // before buf reuse

    // ---- phase B: recompute logits over own s-half, write normalized attn_g ----
    float* bw = (float*)sm + w * 16 * 36;         // per-wave [16][36]
    float* ab = attn_out + (size_t)(b * 8 + h) * 127 * 4096;
    const int srow = lane >> 3;                   // 0..7
    const int scol = (lane & 7) * 4;              // 0..28

    for (int s0 = sbeg; s0 < send; s0 += 32) {
        #pragma unroll
        for (int kk = 0; kk < 2; ++kk) {
            int sg = s0 + kk * 16 + l16;
            s16x8 kf = *(const s16x8*)(kbase + (size_t)sg * 256);
            f32x4 lg = __builtin_amdgcn_mfma_f32_16x16x32_bf16(qf, kf, zero, 0, 0, 0);
            #pragma unroll
            for (int r = 0; r < 4; ++r)
                bw[(hi * 4 + r) * 36 + kk * 16 + l16] = exp2f(lg[r]) * rinv[r];
        }
        #pragma unroll
        for (int rb = 0; rb < 2; ++rb) {
            int row = rb * 8 + srow;
            int mg = qg * 16 + row;
            f32x4 v = *(const f32x4*)(bw + row * 36 + scol);
            if (mg < 127)
                *(f32x4*)(ab + (size_t)mg * 4096 + s0 + scol) = v;
        }
    }
}

// ---------------- gemm_lnhh: Hb = LN(ob@Wo^T + Q(csum)) ----------------
__global__ __launch_bounds__(256) void gemm_lnhh(const u16* __restrict__ A,
        const u16* __restrict__ W, const float* __restrict__ csum,
        const float* __restrict__ a_ws, const float* __restrict__ c_ws,
        u16* __restrict__ Hb)
{
    __shared__ __align__(16) char sm[67584];
    __shared__ float aa[256], cc2[256];
    float (*Cs)[264] = (float(*)[264])sm;
    const int t = threadIdx.x;
    const int r0 = blockIdx.x * 64;
    const int lane = t & 63, w = t >> 6;
    const int l16 = lane & 15, hi = lane >> 4;

    aa[t] = a_ws[t] * 0.015625f;
    cc2[t] = c_ws[t];

    const u16* Ag = A + (size_t)r0 * 256;
    #pragma unroll
    for (int i = 0; i < 8; ++i) {
        int c = t + i * 256;
        int row = c >> 5, c16 = c & 31;
        s16x8 v = *(const s16x8*)(Ag + row * 256 + c16 * 8);
        int boff = (c16 * 16) ^ ((row & 7) << 4);
        *(s16x8*)(sm + row * 512 + boff) = v;
    }
    __syncthreads();

    const int n0 = w * 64;
    f32x4 zero = {0, 0, 0, 0};
    f32x4 acc[4][4];
    #pragma unroll
    for (int mi = 0; mi < 4; ++mi)
        #pragma unroll
        for (int ni = 0; ni < 4; ++ni) acc[mi][ni] = zero;
    #pragma unroll
    for (int kk = 0; kk < 8; ++kk) {
        s16x8 af[4], bf[4];
        #pragma unroll
        for (int mi = 0; mi < 4; ++mi) {
            int row = mi * 16 + l16;
            int boff = (kk * 64 + hi * 16) ^ ((row & 7) << 4);
            af[mi] = *(const s16x8*)(sm + row * 512 + boff);
        }
        #pragma unroll
        for (int ni = 0; ni < 4; ++ni)
            bf[ni] = *(const s16x8*)(W + (n0 + ni * 16 + l16) * 256 + kk * 32 + hi * 8);
        #pragma unroll
        for (int mi = 0; mi < 4; ++mi)
            #pragma unroll
            for (int ni = 0; ni < 4; ++ni)
                acc[mi][ni] = __builtin_amdgcn_mfma_f32_16x16x32_bf16(af[mi], bf[ni], acc[mi][ni], 0, 0, 0);
    }
    __syncthreads();
    #pragma unroll
    for (int mi = 0; mi < 4; ++mi)
        #pragma unroll
        for (int ni = 0; ni < 4; ++ni) {
            int col = n0 + ni * 16 + l16;
            int rowb = mi * 16 + hi * 4;
            #pragma unroll
            for (int r = 0; r < 4; ++r)
                Cs[rowb + r][col] = acc[mi][ni][r];
        }
    __syncthreads();
    for (int pass = 0; pass < 16; ++pass) {
        int row = pass * 4 + w;
        int g = r0 + row, mm = g & 127;
        float v[4];
        #pragma unroll
        for (int j = 0; j < 4; ++j) {
            int d = lane + j * 64;
            float qv = 0.0f;
            if (mm != 127)
                qv = (csum[(size_t)g * 256 + d] + csum[(size_t)(g + 1) * 256 + d]) * aa[d] + cc2[d];
            v[j] = Cs[row][d] + qv;
        }
        float s = v[0] + v[1] + v[2] + v[3];
        for (int m = 32; m; m >>= 1) s += __shfl_xor(s, m);
        float mean = s * (1.0f / 256.0f);
        float q = 0;
        #pragma unroll
        for (int j = 0; j < 4; ++j) { float d_ = v[j] - mean; q += d_ * d_; }
        for (int m = 32; m; m >>= 1) q += __shfl_xor(q, m);
        float rs = rsqrtf(q * (1.0f / 256.0f) + 1e-5f);
        #pragma unroll
        for (int j = 0; j < 4; ++j)
            Hb[(size_t)g * 256 + lane + j * 64] = f2b((v[j] - mean) * rs);
    }
}

// ---------------- decoder attention ----------------
__global__ __launch_bounds__(256) void dec_attn_k(const float* __restrict__ q2,
        const u16* __restrict__ k2b, const u16* __restrict__ v2b,
        float* __restrict__ attn_d, u16* __restrict__ o2b)
{
    __shared__ float qs2[24 * 32];
    __shared__ float ks[128][33];
    __shared__ float vs[128][33];
    __shared__ float lg2[24 * 128];
    __shared__ float sinv[24];
    int bid = blockIdx.x, b = bid >> 3, h = bid & 7;
    int t = threadIdx.x;
    const float scale = 0.17677669529663687f;
    for (int idx = t; idx < 4096; idx += 256) {
        int row = idx >> 5, c = idx & 31;
        ks[row][c] = b2f(k2b[((size_t)(b * 128 + row)) * 256 + h * 32 + c]);
        vs[row][c] = b2f(v2b[((size_t)(b * 128 + row)) * 256 + h * 32 + c]);
    }
    for (int idx = t; idx < 768; idx += 256) {
        int p = idx >> 5, i = idx & 31;
        qs2[idx] = q2[p * 256 + h * 32 + i];
    }
    __syncthreads();
    for (int idx = t; idx < 3048; idx += 256) {
        int p = idx / 127, m = idx - p * 127;
        float s = 0;
        #pragma unroll 8
        for (int i = 0; i < 32; ++i) s += qs2[p * 32 + i] * ks[m][i];
        lg2[p * 128 + m] = __expf(s * scale);
    }
    __syncthreads();
    if (t < 24) {
        float s = 0;
        for (int m = 0; m < 127; ++m) s += lg2[t * 128 + m];
        sinv[t] = 1.0f / s;
    }
    __syncthreads();
    float* ad = attn_d + (size_t)bid * 24 * 127;
    for (int idx = t; idx < 3048; idx += 256) {
        int p = idx / 127, m = idx - p * 127;
        float av = lg2[p * 128 + m] * sinv[p];
        lg2[p * 128 + m] = av;
        ad[idx] = av;
    }
    __syncthreads();
    for (int idx = t; idx < 768; idx += 256) {
        int p = idx >> 5, dh = idx & 31;
        float s = 0;
        for (int m = 0; m < 127; ++m)
            s += lg2[p * 128 + m] * vs[m][dh];
        o2b[((size_t)(b * 24 + p)) * 256 + h * 32 + dh] = f2b(s);
    }
}

// ---------------- gemm_ln3: z2 = LN(o2b@Wo2^T + Qd) -> z2f + z2b ----------------
__global__ __launch_bounds__(256) void gemm_ln3(const u16* __restrict__ A,
        const u16* __restrict__ W, const float* __restrict__ dec_Qd,
        float* __restrict__ z2f, u16* __restrict__ z2b)
{
    __shared__ __align__(16) char sm[67584];
    float (*Cs)[264] = (float(*)[264])sm;
    const int t = threadIdx.x;
    const int r0 = blockIdx.x * 64;
    const int lane = t & 63, w = t >> 6;
    const int l16 = lane & 15, hi = lane >> 4;

    const u16* Ag = A + (size_t)r0 * 256;
    #pragma unroll
    for (int i = 0; i < 8; ++i) {
        int c = t + i * 256;
        int row = c >> 5, c16 = c & 31;
        s16x8 v = *(const s16x8*)(Ag + row * 256 + c16 * 8);
        int boff = (c16 * 16) ^ ((row & 7) << 4);
        *(s16x8*)(sm + row * 512 + boff) = v;
    }
    __syncthreads();

    const int n0 = w * 64;
    f32x4 zero = {0, 0, 0, 0};
    f32x4 acc[4][4];
    #pragma unroll
    for (int mi = 0; mi < 4; ++mi)
        #pragma unroll
        for (int ni = 0; ni < 4; ++ni) acc[mi][ni] = zero;
    #pragma unroll
    for (int kk = 0; kk < 8; ++kk) {
        s16x8 af[4], bf[4];
        #pragma unroll
        for (int mi = 0; mi < 4; ++mi) {
            int row = mi * 16 + l16;
            int boff = (kk * 64 + hi * 16) ^ ((row & 7) << 4);
            af[mi] = *(const s16x8*)(sm + row * 512 + boff);
        }
        #pragma unroll
        for (int ni = 0; ni < 4; ++ni)
            bf[ni] = *(const s16x8*)(W + (n0 + ni * 16 + l16) * 256 + kk * 32 + hi * 8);
        #pragma unroll
        for (int mi = 0; mi < 4; ++mi)
            #pragma unroll
            for (int ni = 0; ni < 4; ++ni)
                acc[mi][ni] = __builtin_amdgcn_mfma_f32_16x16x32_bf16(af[mi], bf[ni], acc[mi][ni], 0, 0, 0);
    }
    __syncthreads();
    #pragma unroll
    for (int mi = 0; mi < 4; ++mi)
        #pragma unroll
        for (int ni = 0; ni < 4; ++ni) {
            int col = n0 + ni * 16 + l16;
            int rowb = mi * 16 + hi * 4;
            #pragma unroll
            for (int r = 0; r < 4; ++r)
                Cs[rowb + r][col] = acc[mi][ni][r];
        }
    __syncthreads();
    for (int pass = 0; pass < 16; ++pass) {
        int row = pass * 4 + w;
        int g = r0 + row, p = g % 24;
        float v[4];
        #pragma unroll
        for (int j = 0; j < 4; ++j) {
            int d = lane + j * 64;
            v[j] = Cs[row][d] + dec_Qd[p * 256 + d];
        }
        float s = v[0] + v[1] + v[2] + v[3];
        for (int m = 32; m; m >>= 1) s += __shfl_xor(s, m);
        float mean = s * (1.0f / 256.0f);
        float q = 0;
        #pragma unroll
        for (int j = 0; j < 4; ++j) { float d_ = v[j] - mean; q += d_ * d_; }
        for (int m = 32; m; m >>= 1) q += __shfl_xor(q, m);
        float rs = rsqrtf(q * (1.0f / 256.0f) + 1e-5f);
        #pragma unroll
        for (int j = 0; j < 4; ++j) {
            float u = (v[j] - mean) * rs;
            z2f[(size_t)g * 256 + lane + j * 64] = u;
            z2b[(size_t)g * 256 + lane + j * 64] = f2b(u);
        }
    }
}

// ---------------- gemm_ln5: u = LN(u1b@ff2^T + b2 + z2f); y = coef*(u.out_w + out_b) ----------------
__global__ __launch_bounds__(256) void gemm_ln5(const u16* __restrict__ A,
        const u16* __restrict__ W, const float* __restrict__ bias,
        const float* __restrict__ z2f, const float* __restrict__ out_w,
        const float* __restrict__ out_b, const float* __restrict__ coef,
        float* __restrict__ y)
{
    __shared__ __align__(16) char sm[67584];
    float (*Cs)[264] = (float(*)[264])sm;
    const int t = threadIdx.x;
    const int r0 = blockIdx.x * 64;
    const int lane = t & 63, w = t >> 6;
    const int l16 = lane & 15, hi = lane >> 4;
    const int K = 512;

    const u16* Ag = A + (size_t)r0 * K;
    const int n0 = w * 64;
    f32x4 zero = {0, 0, 0, 0};
    f32x4 acc[4][4];
    #pragma unroll
    for (int mi = 0; mi < 4; ++mi)
        #pragma unroll
        for (int ni = 0; ni < 4; ++ni) acc[mi][ni] = zero;

    for (int kc = 0; kc < K; kc += 256) {
        if (kc) __syncthreads();
        #pragma unroll
        for (int i = 0; i < 8; ++i) {
            int c = t + i * 256;
            int row = c >> 5, c16 = c & 31;
            s16x8 v = *(const s16x8*)(Ag + (size_t)row * K + kc + c16 * 8);
            int boff = (c16 * 16) ^ ((row & 7) << 4);
            *(s16x8*)(sm + row * 512 + boff) = v;
        }
        __syncthreads();
        #pragma unroll
        for (int kk = 0; kk < 8; ++kk) {
            s16x8 af[4], bf[4];
            #pragma unroll
            for (int mi = 0; mi < 4; ++mi) {
                int row = mi * 16 + l16;
                int boff = (kk * 64 + hi * 16) ^ ((row & 7) << 4);
                af[mi] = *(const s16x8*)(sm + row * 512 + boff);
            }
            #pragma unroll
            for (int ni = 0; ni < 4; ++ni)
                bf[ni] = *(const s16x8*)(W + (size_t)(n0 + ni * 16 + l16) * K + kc + kk * 32 + hi * 8);
            #pragma unroll
            for (int mi = 0; mi < 4; ++mi)
                #pragma unroll
                for (int ni = 0; ni < 4; ++ni)
                    acc[mi][ni] = __builtin_amdgcn_mfma_f32_16x16x32_bf16(af[mi], bf[ni], acc[mi][ni], 0, 0, 0);
        }
    }
    __syncthreads();
    #pragma unroll
    for (int mi = 0; mi < 4; ++mi)
        #pragma unroll
        for (int ni = 0; ni < 4; ++ni) {
            int col = n0 + ni * 16 + l16;
            int rowb = mi * 16 + hi * 4;
            #pragma unroll
            for (int r = 0; r < 4; ++r)
                Cs[rowb + r][col] = acc[mi][ni][r];
        }
    __syncthreads();
    for (int pass = 0; pass < 16; ++pass) {
        int row = pass * 4 + w;
        int g = r0 + row, p = g % 24;
        float v[4];
        #pragma unroll
        for (int j = 0; j < 4; ++j) {
            int d = lane + j * 64;
            v[j] = Cs[row][d] + bias[d] + z2f[(size_t)g * 256 + d];
        }
        float s = v[0] + v[1] + v[2] + v[3];
        for (int m = 32; m; m >>= 1) s += __shfl_xor(s, m);
        float mean = s * (1.0f / 256.0f);
        float q = 0;
        #pragma unroll
        for (int j = 0; j < 4; ++j) { float d_ = v[j] - mean; q += d_ * d_; }
        for (int m = 32; m; m >>= 1) q += __shfl_xor(q, m);
        float rs = rsqrtf(q * (1.0f / 256.0f) + 1e-5f);
        float yp = 0;
        #pragma unroll
        for (int j = 0; j < 4; ++j)
            yp += (v[j] - mean) * rs * out_w[lane + j * 64];
        for (int m = 32; m; m >>= 1) yp += __shfl_xor(yp, m);
        if (lane == 0)
            y[g] = coef[p] * (yp + out_b[0]);
    }
}

extern "C" void kernel_launch(void* const* d_in, const int* in_sizes, int n_in,
                              void* d_out, int out_size, void* d_ws, size_t ws_size,
                              hipStream_t stream)
{
    const float* x        = (const float*)d_in[0];
    const float* dw_w     = (const float*)d_in[2];
    const float* pw_w     = (const float*)d_in[3];
    const float* bn_g     = (const float*)d_in[4];
    const float* bn_b     = (const float*)d_in[5];
    const float* lg_Wq    = (const float*)d_in[6];
    const float* lg_Wk    = (const float*)d_in[7];
    const float* lg_Wv    = (const float*)d_in[8];
    const float* lg_Wo    = (const float*)d_in[9];
    const float* dec_Qd   = (const float*)d_in[10];
    const float* dec_Wq   = (const float*)d_in[11];
    const float* dec_Wk   = (const float*)d_in[12];
    const float* dec_Wv   = (const float*)d_in[13];
    const float* dec_Wo   = (const float*)d_in[14];
    const float* ff1_w    = (const float*)d_in[15];
    const float* ff1_b    = (const float*)d_in[16];
    const float* ff2_w    = (const float*)d_in[17];
    const float* ff2_b    = (const float*)d_in[18];
    const float* out_w    = (const float*)d_in[19];
    const float* out_b    = (const float*)d_in[20];
    const float* gate_lg  = (const float*)d_in[21];

    char* ws = (char*)d_ws;
    size_t off = 0;
    auto alloc = [&](size_t bytes) -> void* {
        void* p = ws + off;
        off = (off + bytes + 255) & ~(size_t)255;
        return p;
    };
    u16*   zp    = (u16*)  alloc(67108864);   // [B*S,256] bf16 post-gelu
    u16*   kb    = (u16*)  alloc(67108864);   // K [B*S,256] bf16
    u16*   vT    = (u16*)  alloc(67108864);   // V blocked [b*8+h][sblk][dh][64] bf16
    float* csum  = (float*)alloc(4194304);
    float* csum2 = (float*)alloc(4194304);
    u16*   qb    = (u16*)  alloc(2097152);
    u16*   ob    = (u16*)  alloc(2097152);
    u16*   Hb    = (u16*)  alloc(2097152);
    u16*   k2b   = (u16*)  alloc(2097152);
    u16*   v2b   = (u16*)  alloc(2097152);
    u16*   o2b   = (u16*)  alloc(393216);
    float* z2f   = (float*)alloc(786432);
    u16*   z2b   = (u16*)  alloc(393216);
    u16*   u1b   = (u16*)  alloc(786432);
    float* q2    = (float*)alloc(24576);
    float* statp = (float*)alloc(131072);
    float* a_ws  = (float*)alloc(1024);
    float* c_ws  = (float*)alloc(1024);
    float* betak = (float*)alloc(1024);
    float* betav = (float*)alloc(1024);
    float* coef  = (float*)alloc(256);
    u16*   pwb   = (u16*)  alloc(16384);
    u16*   Wk_b  = (u16*)  alloc(131072);
    u16*   Wv_b  = (u16*)  alloc(131072);
    u16*   Wq_b  = (u16*)  alloc(131072);
    u16*   Wo_b  = (u16*)  alloc(131072);
    u16*   Wk2_b = (u16*)  alloc(131072);
    u16*   Wv2_b = (u16*)  alloc(131072);
    u16*   Wo2b  = (u16*)  alloc(131072);
    u16*   ff1b  = (u16*)  alloc(262144);
    u16*   ff2b  = (u16*)  alloc(262144);

    float* y_out  = (float*)d_out;
    float* attn_g = y_out + 768;
    float* attn_d = attn_g + (size_t)32 * 8 * 127 * 4096;

    prep0_k<<<2336, 256, 0, stream>>>(pw_w, lg_Wq, lg_Wo, dec_Wk, dec_Wv, dec_Wo, ff1_w, ff2_w,
                                      pwb, Wq_b, Wo_b, Wk2_b, Wv2_b, Wo2b, ff1b, ff2b);
    dwpw_k<<<2048, 256, 0, stream>>>(x, dw_w, pwb, zp, csum, csum2);
    stats2_k<<<64, 256, 0, stream>>>(csum, csum2, statp);
    prep1_k<<<1, 256, 0, stream>>>(statp, bn_g, bn_b, gate_lg, a_ws, c_ws, coef);
    prepx_k<<<592, 256, 0, stream>>>(lg_Wk, lg_Wv, a_ws, c_ws, dec_Qd, dec_Wq, csum, Wq_b,
                                     Wk_b, Wv_b, betak, betav, q2, qb);
    kv_k<<<2048, 256, 0, stream>>>(zp, Wk_b, Wv_b, betak, betav, kb, vT);
    attn_k<<<256, 1024, 0, stream>>>(qb, kb, vT, ob, attn_g);
    gemm_lnhh<<<64, 256, 0, stream>>>(ob, Wo_b, csum, a_ws, c_ws, Hb);
    gemm_dual<<<128, 256, 0, stream>>>(Hb, Wk2_b, Wv2_b, k2b, v2b);
    dec_attn_k<<<256, 256, 0, stream>>>(q2, k2b, v2b, attn_d, o2b);
    gemm_ln3<<<12, 256, 0, stream>>>(o2b, Wo2b, dec_Qd, z2f, z2b);
    gemm_g<2><<<24, 256, 0, stream>>>(z2b, ff1b, ff1_b, u1b, 256, 2);
    gemm_ln5<<<12, 256, 0, stream>>>(u1b, ff2b, ff2_b, z2f, out_w, out_b, coef, y_out);
}

// Round 12
// 600.020 us; speedup vs baseline: 1.0258x; 1.0258x over previous
//
#include <hip/hip_runtime.h>
#include <hip/hip_bf16.h>
#include <cmath>

typedef unsigned short u16;
typedef __attribute__((ext_vector_type(4))) float f32x4;
typedef __attribute__((ext_vector_type(8))) short s16x8;

__device__ __forceinline__ float b2f(u16 u) { return __uint_as_float(((unsigned)u) << 16); }
__device__ __forceinline__ u16 f2b(float f) {
    unsigned u = __float_as_uint(f);
    unsigned r = (u + 0x7fffu + ((u >> 16) & 1u)) >> 16;
    return (u16)r;
}
// tanh-based gelu: |err| < ~1e-3 for our |x|<1.5 -- within bf16 tolerance
__device__ __forceinline__ float gelu_f(float x) {
    float t = x * (0.7978845608f + 0.0356774081f * x * x);
    float e = exp2f(2.885390082f * t);
    return 0.5f * x * (1.0f + (e - 1.0f) / (e + 1.0f));
}

#define FOLD 0.25503590f   // (1/sqrt(32)) * log2(e)

// ---------------- prep0: cast weights to bf16 ----------------
__global__ __launch_bounds__(256) void prep0_k(const float* __restrict__ pw_w,
        const float* __restrict__ lg_Wq, const float* __restrict__ lg_Wo,
        const float* __restrict__ dec_Wk, const float* __restrict__ dec_Wv,
        const float* __restrict__ dec_Wo, const float* __restrict__ ff1_w,
        const float* __restrict__ ff2_w,
        u16* __restrict__ pwb, u16* __restrict__ Wq_b, u16* __restrict__ Wo_b,
        u16* __restrict__ Wk2_b, u16* __restrict__ Wv2_b, u16* __restrict__ Wo2b,
        u16* __restrict__ ff1b, u16* __restrict__ ff2b)
{
    int idx = blockIdx.x * 256 + threadIdx.x;     // 598016 total
    if (idx < 327680) {
        int which = idx >> 16, r = idx & 65535;
        const float* srcs[5] = {lg_Wq, lg_Wo, dec_Wk, dec_Wv, dec_Wo};
        u16* dsts[5] = {Wq_b, Wo_b, Wk2_b, Wv2_b, Wo2b};
        dsts[which][r] = f2b(srcs[which][r]);
    } else if (idx < 458752) {
        int r = idx - 327680;
        ff1b[r] = f2b(ff1_w[r]);
    } else if (idx < 589824) {
        int r = idx - 458752;
        ff2b[r] = f2b(ff2_w[r]);
    } else {
        int r = idx - 589824;
        pwb[r] = f2b(pw_w[r]);
    }
}

// ---------------- fused frontend: depthwise + pointwise MFMA + gelu + stat sums ----------------
__global__ __launch_bounds__(256) void dwpw_k(const float* __restrict__ x,
        const float* __restrict__ dw_w, const u16* __restrict__ pwb,
        u16* __restrict__ zp, float* __restrict__ csum, float* __restrict__ csum2)
{
    __shared__ float xs[68][33];
    __shared__ __align__(16) u16 As[64][40];
    const int t = threadIdx.x;
    const int b = blockIdx.x >> 6, s0 = (blockIdx.x & 63) << 6;
    const int r0 = blockIdx.x * 64;
    const int lane = t & 63, w = t >> 6;
    const int l16 = lane & 15, hi = lane >> 4;

    for (int idx = t; idx < 68 * 32; idx += 256) {
        int row = idx >> 5, c = idx & 31;
        int sg = s0 - 2 + row;
        xs[row][c] = (sg >= 0 && sg < 4096) ? x[((size_t)b * 4096 + sg) * 32 + c] : 0.0f;
    }
    const int cc = t & 31;
    float wv[5];
    #pragma unroll
    for (int k = 0; k < 5; ++k) wv[k] = dw_w[cc * 5 + k];
    __syncthreads();
    #pragma unroll
    for (int i = 0; i < 8; ++i) {
        int sl = (t + i * 256) >> 5;
        float acc = 0;
        #pragma unroll
        for (int k = 0; k < 5; ++k) acc += xs[sl + k][cc] * wv[k];
        As[sl][cc] = f2b(acc);
    }
    __syncthreads();

    const int n0 = w * 64;
    f32x4 zero = {0, 0, 0, 0};
    s16x8 bf[4];
    #pragma unroll
    for (int ni = 0; ni < 4; ++ni)
        bf[ni] = *(const s16x8*)(pwb + (n0 + ni * 16 + l16) * 32 + hi * 8);

    float cl[4] = {0,0,0,0}, ch[4] = {0,0,0,0};
    float ql[4] = {0,0,0,0}, qh[4] = {0,0,0,0};

    #pragma unroll
    for (int mi = 0; mi < 4; ++mi) {
        s16x8 af = *(const s16x8*)&As[mi * 16 + l16][hi * 8];
        #pragma unroll
        for (int ni = 0; ni < 4; ++ni) {
            f32x4 acc = __builtin_amdgcn_mfma_f32_16x16x32_bf16(af, bf[ni], zero, 0, 0, 0);
            int col = n0 + ni * 16 + l16;
            int rowb = r0 + mi * 16 + hi * 4;
            #pragma unroll
            for (int r = 0; r < 4; ++r) {
                float e = gelu_f(acc[r]);
                zp[(size_t)(rowb + r) * 256 + col] = f2b(e);
                if (mi < 2) { cl[ni] += e; ql[ni] += e * e; }
                else        { ch[ni] += e; qh[ni] += e * e; }
            }
        }
    }
    #pragma unroll
    for (int ni = 0; ni < 4; ++ni) {
        #pragma unroll
        for (int m = 16; m <= 32; m <<= 1) {
            cl[ni] += __shfl_xor(cl[ni], m);
            ch[ni] += __shfl_xor(ch[ni], m);
            ql[ni] += __shfl_xor(ql[ni], m);
            qh[ni] += __shfl_xor(qh[ni], m);
        }
        if (lane < 16) {
            int col = n0 + ni * 16 + lane;
            size_t bc = (size_t)(r0 >> 5);
            csum [bc * 256 + col]       = cl[ni];
            csum [(bc + 1) * 256 + col] = ch[ni];
            csum2[bc * 256 + col]       = ql[ni];
            csum2[(bc + 1) * 256 + col] = qh[ni];
        }
    }
}

// ---------------- stats2 ----------------
__global__ __launch_bounds__(256) void stats2_k(const float* __restrict__ csum,
        const float* __restrict__ csum2, float* __restrict__ statp)
{
    int j = blockIdx.x, t = threadIdx.x;
    float s1 = 0, s2 = 0;
    for (int i = 0; i < 64; ++i) {
        s1 += csum [(size_t)(j * 64 + i) * 256 + t];
        s2 += csum2[(size_t)(j * 64 + i) * 256 + t];
    }
    statp[j * 512 + t] = s1;
    statp[j * 512 + 256 + t] = s2;
}

// ---------------- prep1: BN affine + gate coef ----------------
__global__ __launch_bounds__(256) void prep1_k(const float* __restrict__ statp,
        const float* __restrict__ bn_g, const float* __restrict__ bn_b,
        const float* __restrict__ gate_logits,
        float* __restrict__ a_ws, float* __restrict__ c_ws, float* __restrict__ coef)
{
    int t = threadIdx.x;
    float s1 = 0, s2 = 0;
    for (int j = 0; j < 64; ++j) {
        s1 += statp[j * 512 + t];
        s2 += statp[j * 512 + 256 + t];
    }
    const float invN = 1.0f / 131072.0f;
    float mean = s1 * invN;
    float var = s2 * invN - mean * mean;
    float av = bn_g[t] * rsqrtf(var + 1e-5f);
    a_ws[t] = av;
    c_ws[t] = bn_b[t] - mean * av;
    if (t < 24) {
        float g0 = gate_logits[t * 3], g1 = gate_logits[t * 3 + 1], g2 = gate_logits[t * 3 + 2];
        float mx = fmaxf(g0, fmaxf(g1, g2));
        float e0 = __expf(g0 - mx), e1 = __expf(g1 - mx), e2 = __expf(g2 - mx);
        coef[t] = (e1 + e2) / (e0 + e1 + e2);
    }
}

// ---------------- prepx: prep2b (512) + q2 (16) + qgemm (64) in one dispatch ----------------
__global__ __launch_bounds__(256) void prepx_k(const float* __restrict__ lg_Wk,
        const float* __restrict__ lg_Wv, const float* __restrict__ a_ws,
        const float* __restrict__ c_ws, const float* __restrict__ dec_Qd,
        const float* __restrict__ dec_Wq, const float* __restrict__ csum,
        const u16* __restrict__ Wq_b,
        u16* __restrict__ Wk_b, u16* __restrict__ Wv_b,
        float* __restrict__ betak, float* __restrict__ betav,
        float* __restrict__ q2, u16* __restrict__ qb)
{
    __shared__ __align__(16) char sm[41728];
    const int bid = blockIdx.x, t = threadIdx.x;
    if (bid < 512) {
        float* red = (float*)sm;
        int which = bid >> 8, row = bid & 255;
        const float* Wsrc = which ? lg_Wv : lg_Wk;
        float wv = Wsrc[row * 256 + t];
        (which ? Wv_b : Wk_b)[row * 256 + t] = f2b(wv * a_ws[t]);
        float v = wv * c_ws[t];
        for (int m = 32; m; m >>= 1) v += __shfl_xor(v, m);
        if ((t & 63) == 0) red[t >> 6] = v;
        __syncthreads();
        if (t == 0) (which ? betav : betak)[row] = red[0] + red[1] + red[2] + red[3];
    } else if (bid < 528) {
        float (*wq)[260] = (float(*)[260])sm;
        float (*qd)[260] = (float(*)[260])(sm + 16640);
        int j = bid - 512;
        for (int idx = t; idx < 4096; idx += 256) {
            int tl = idx >> 8, d = idx & 255;
            wq[tl][d] = dec_Wq[(j * 16 + tl) * 256 + d];
        }
        for (int idx = t; idx < 6144; idx += 256) {
            int p = idx >> 8, d = idx & 255;
            qd[p][d] = dec_Qd[idx];
        }
        __syncthreads();
        for (int o = t; o < 384; o += 256) {
            int p = o >> 4, tl = o & 15;
            float s = 0;
            #pragma unroll 8
            for (int d = 0; d < 256; ++d) s += qd[p][d] * wq[tl][d];
            q2[p * 256 + j * 16 + tl] = s;
        }
    } else {
        u16* As = (u16*)sm;                       // 32KB
        float* aa = (float*)(sm + 32768);
        float* ccx = (float*)(sm + 33792);
        const int r0 = (bid - 528) * 64;
        const int lane = t & 63, w = t >> 6;
        const int l16 = lane & 15, hi = lane >> 4;
        aa[t] = a_ws[t] * 0.015625f;
        ccx[t] = c_ws[t];
        __syncthreads();
        #pragma unroll
        for (int i = 0; i < 8; ++i) {
            int c = t + i * 256;
            int row = c >> 5, c16 = c & 31;
            int g = r0 + row, mm = g & 127;
            u16 tmp[8];
            if (mm == 127) {
                #pragma unroll
                for (int j = 0; j < 8; ++j) tmp[j] = 0;
            } else {
                const float* c0p = csum + (size_t)g * 256 + c16 * 8;
                const float* c1p = c0p + 256;
                #pragma unroll
                for (int j = 0; j < 8; ++j) {
                    int d = c16 * 8 + j;
                    tmp[j] = f2b((c0p[j] + c1p[j]) * aa[d] + ccx[d]);
                }
            }
            int boff = (c16 * 16) ^ ((row & 7) << 4);
            *(s16x8*)((char*)As + row * 512 + boff) = *(s16x8*)tmp;
        }
        __syncthreads();
        const int n0 = w * 64;
        f32x4 zero = {0, 0, 0, 0};
        f32x4 acc[4][4];
        #pragma unroll
        for (int mi = 0; mi < 4; ++mi)
            #pragma unroll
            for (int ni = 0; ni < 4; ++ni) acc[mi][ni] = zero;
        #pragma unroll
        for (int kk = 0; kk < 8; ++kk) {
            s16x8 af[4], bf[4];
            #pragma unroll
            for (int mi = 0; mi < 4; ++mi) {
                int row = mi * 16 + l16;
                int boff = (kk * 64 + hi * 16) ^ ((row & 7) << 4);
                af[mi] = *(const s16x8*)((const char*)As + row * 512 + boff);
            }
            #pragma unroll
            for (int ni = 0; ni < 4; ++ni)
                bf[ni] = *(const s16x8*)(Wq_b + (n0 + ni * 16 + l16) * 256 + kk * 32 + hi * 8);
            #pragma unroll
            for (int mi = 0; mi < 4; ++mi)
                #pragma unroll
                for (int ni = 0; ni < 4; ++ni)
                    acc[mi][ni] = __builtin_amdgcn_mfma_f32_16x16x32_bf16(af[mi], bf[ni], acc[mi][ni], 0, 0, 0);
        }
        #pragma unroll
        for (int mi = 0; mi < 4; ++mi)
            #pragma unroll
            for (int ni = 0; ni < 4; ++ni) {
                int col = n0 + ni * 16 + l16;
                int rowb = r0 + mi * 16 + hi * 4;
                #pragma unroll
                for (int r = 0; r < 4; ++r)
                    qb[(size_t)(rowb + r) * 256 + col] = f2b(acc[mi][ni][r] * FOLD);
            }
    }
}

// ---------------- fused K/V projection: kb row-major + vT blocked-transposed ----------------
// vT layout: [b*8+h][sblk(64)][dh(32)][sl(64)]
__global__ __launch_bounds__(256) void kv_k(const u16* __restrict__ zp,
        const u16* __restrict__ Wk, const u16* __restrict__ Wv,
        const float* __restrict__ betak, const float* __restrict__ betav,
        u16* __restrict__ kb, u16* __restrict__ vT)
{
    __shared__ __align__(16) char smem[36864];
    const int t = threadIdx.x;
    const int r0 = blockIdx.x * 64;
    const int lane = t & 63, w = t >> 6;
    const int l16 = lane & 15, hi = lane >> 4;

    const u16* Ag = zp + (size_t)r0 * 256;
    #pragma unroll
    for (int i = 0; i < 8; ++i) {
        int c = t + i * 256;
        int row = c >> 5, c16 = c & 31;
        s16x8 v = *(const s16x8*)(Ag + row * 256 + c16 * 8);
        int boff = (c16 * 16) ^ ((row & 7) << 4);
        *(s16x8*)(smem + row * 512 + boff) = v;
    }
    __syncthreads();

    const int n0 = w * 64;
    f32x4 zero = {0, 0, 0, 0};
    f32x4 acc[4][4];
    #pragma unroll
    for (int mi = 0; mi < 4; ++mi)
        #pragma unroll
        for (int ni = 0; ni < 4; ++ni) acc[mi][ni] = zero;

    #pragma unroll
    for (int kk = 0; kk < 8; ++kk) {
        s16x8 af[4], bfk[4];
        #pragma unroll
        for (int mi = 0; mi < 4; ++mi) {
            int row = mi * 16 + l16;
            int boff = (kk * 64 + hi * 16) ^ ((row & 7) << 4);
            af[mi] = *(const s16x8*)(smem + row * 512 + boff);
        }
        #pragma unroll
        for (int ni = 0; ni < 4; ++ni)
            bfk[ni] = *(const s16x8*)(Wk + (n0 + ni * 16 + l16) * 256 + kk * 32 + hi * 8);
        #pragma unroll
        for (int mi = 0; mi < 4; ++mi)
            #pragma unroll
            for (int ni = 0; ni < 4; ++ni)
                acc[mi][ni] = __builtin_amdgcn_mfma_f32_16x16x32_bf16(af[mi], bfk[ni], acc[mi][ni], 0, 0, 0);
    }
    #pragma unroll
    for (int mi = 0; mi < 4; ++mi)
        #pragma unroll
        for (int ni = 0; ni < 4; ++ni) {
            int col = n0 + ni * 16 + l16;
            float bv = betak[col];
            int rowb = r0 + mi * 16 + hi * 4;
            #pragma unroll
            for (int r = 0; r < 4; ++r)
                kb[(size_t)(rowb + r) * 256 + col] = f2b(acc[mi][ni][r] + bv);
        }

    #pragma unroll
    for (int mi = 0; mi < 4; ++mi)
        #pragma unroll
        for (int ni = 0; ni < 4; ++ni) acc[mi][ni] = zero;
    #pragma unroll
    for (int kk = 0; kk < 8; ++kk) {
        s16x8 af[4], bfv[4];
        #pragma unroll
        for (int mi = 0; mi < 4; ++mi) {
            int row = mi * 16 + l16;
            int boff = (kk * 64 + hi * 16) ^ ((row & 7) << 4);
            af[mi] = *(const s16x8*)(smem + row * 512 + boff);
        }
        #pragma unroll
        for (int ni = 0; ni < 4; ++ni)
            bfv[ni] = *(const s16x8*)(Wv + (n0 + ni * 16 + l16) * 256 + kk * 32 + hi * 8);
        #pragma unroll
        for (int mi = 0; mi < 4; ++mi)
            #pragma unroll
            for (int ni = 0; ni < 4; ++ni)
                acc[mi][ni] = __builtin_amdgcn_mfma_f32_16x16x32_bf16(af[mi], bfv[ni], acc[mi][ni], 0, 0, 0);
    }
    __syncthreads();
    #pragma unroll
    for (int mi = 0; mi < 4; ++mi)
        #pragma unroll
        for (int ni = 0; ni < 4; ++ni) {
            int col = n0 + ni * 16 + l16;
            float bv = betav[col];
            int rowb = mi * 16 + hi * 4;
            ushort4 pk;
            pk.x = f2b(acc[mi][ni][0] + bv);
            pk.y = f2b(acc[mi][ni][1] + bv);
            pk.z = f2b(acc[mi][ni][2] + bv);
            pk.w = f2b(acc[mi][ni][3] + bv);
            char* p = smem + col * 144 + ((((rowb >> 3) ^ (col & 7)) & 7) << 4) + ((rowb & 7) << 1);
            *(ushort4*)p = pk;
        }
    __syncthreads();
    const int b = r0 >> 12;
    const int sblk = (r0 & 4095) >> 6;
    u16* vout = vT + (size_t)(b * 8) * 131072 + (size_t)sblk * 2048;
    #pragma unroll
    for (int j = 0; j < 8; ++j) {
        int gid = j * 256 + t;
        int col = gid >> 3, oct = gid & 7;
        const char* p = smem + col * 144 + (((oct ^ (col & 7)) & 7) << 4);
        s16x8 v = *(const s16x8*)p;
        int h = col >> 5, dh = col & 31;
        *(s16x8*)(vout + (size_t)h * 131072 + dh * 64 + oct * 8) = v;
    }
}

// ---------------- generic MFMA GEMM (used for ff1 w/ gelu) ----------------
template<int MODE>
__global__ __launch_bounds__(256) void gemm_g(const u16* __restrict__ A,
        const u16* __restrict__ W, const float* __restrict__ bias,
        void* __restrict__ Cout, int K, int ntn)
{
    __shared__ u16 As[64 * 256];
    const int t = threadIdx.x;
    const int rt = blockIdx.x / ntn, nt = blockIdx.x % ntn;
    const int r0 = rt * 64, N = ntn * 256;
    const int lane = t & 63, w = t >> 6;
    const int l16 = lane & 15, hi = lane >> 4;

    const u16* Ag = A + (size_t)r0 * K;
    const int n0 = w * 64;
    f32x4 zero = {0, 0, 0, 0};
    f32x4 acc[4][4];
    #pragma unroll
    for (int mi = 0; mi < 4; ++mi)
        #pragma unroll
        for (int ni = 0; ni < 4; ++ni) acc[mi][ni] = zero;

    for (int kc = 0; kc < K; kc += 256) {
        if (kc) __syncthreads();
        #pragma unroll
        for (int i = 0; i < 8; ++i) {
            int c = t + i * 256;
            int row = c >> 5, c16 = c & 31;
            s16x8 v = *(const s16x8*)(Ag + (size_t)row * K + kc + c16 * 8);
            int boff = (c16 * 16) ^ ((row & 7) << 4);
            *(s16x8*)((char*)As + row * 512 + boff) = v;
        }
        __syncthreads();
        #pragma unroll
        for (int kk = 0; kk < 8; ++kk) {
            s16x8 af[4], bf[4];
            #pragma unroll
            for (int mi = 0; mi < 4; ++mi) {
                int row = mi * 16 + l16;
                int boff = (kk * 64 + hi * 16) ^ ((row & 7) << 4);
                af[mi] = *(const s16x8*)((const char*)As + row * 512 + boff);
            }
            #pragma unroll
            for (int ni = 0; ni < 4; ++ni) {
                int j = nt * 256 + n0 + ni * 16 + l16;
                bf[ni] = *(const s16x8*)(W + (size_t)j * K + kc + kk * 32 + hi * 8);
            }
            #pragma unroll
            for (int mi = 0; mi < 4; ++mi)
                #pragma unroll
                for (int ni = 0; ni < 4; ++ni)
                    acc[mi][ni] = __builtin_amdgcn_mfma_f32_16x16x32_bf16(af[mi], bf[ni], acc[mi][ni], 0, 0, 0);
        }
    }

    #pragma unroll
    for (int mi = 0; mi < 4; ++mi)
        #pragma unroll
        for (int ni = 0; ni < 4; ++ni) {
            int col = nt * 256 + n0 + ni * 16 + l16;
            float bv = bias ? bias[col] : 0.0f;
            int rowb = r0 + mi * 16 + hi * 4;
            #pragma unroll
            for (int r = 0; r < 4; ++r) {
                float v = acc[mi][ni][r] + bv;
                if (MODE == 0)      ((u16*)Cout)[(size_t)(rowb + r) * N + col] = f2b(v);
                else if (MODE == 1) ((float*)Cout)[(size_t)(rowb + r) * N + col] = v;
                else                ((u16*)Cout)[(size_t)(rowb + r) * N + col] = f2b(gelu_f(v));
            }
        }
}

// ---------------- dual 256-K GEMM: Hb -> k2b / v2b ----------------
__global__ __launch_bounds__(256) void gemm_dual(const u16* __restrict__ A,
        const u16* __restrict__ W0, const u16* __restrict__ W1,
        u16* __restrict__ C0, u16* __restrict__ C1)
{
    __shared__ u16 As[64 * 256];
    const int t = threadIdx.x;
    const int which = blockIdx.x >> 6;
    const int r0 = (blockIdx.x & 63) * 64;
    const u16* W = which ? W1 : W0;
    u16* C = which ? C1 : C0;
    const int lane = t & 63, w = t >> 6;
    const int l16 = lane & 15, hi = lane >> 4;

    const u16* Ag = A + (size_t)r0 * 256;
    #pragma unroll
    for (int i = 0; i < 8; ++i) {
        int c = t + i * 256;
        int row = c >> 5, c16 = c & 31;
        s16x8 v = *(const s16x8*)(Ag + row * 256 + c16 * 8);
        int boff = (c16 * 16) ^ ((row & 7) << 4);
        *(s16x8*)((char*)As + row * 512 + boff) = v;
    }
    __syncthreads();

    const int n0 = w * 64;
    f32x4 zero = {0, 0, 0, 0};
    f32x4 acc[4][4];
    #pragma unroll
    for (int mi = 0; mi < 4; ++mi)
        #pragma unroll
        for (int ni = 0; ni < 4; ++ni) acc[mi][ni] = zero;

    #pragma unroll
    for (int kk = 0; kk < 8; ++kk) {
        s16x8 af[4], bf[4];
        #pragma unroll
        for (int mi = 0; mi < 4; ++mi) {
            int row = mi * 16 + l16;
            int boff = (kk * 64 + hi * 16) ^ ((row & 7) << 4);
            af[mi] = *(const s16x8*)((const char*)As + row * 512 + boff);
        }
        #pragma unroll
        for (int ni = 0; ni < 4; ++ni)
            bf[ni] = *(const s16x8*)(W + (n0 + ni * 16 + l16) * 256 + kk * 32 + hi * 8);
        #pragma unroll
        for (int mi = 0; mi < 4; ++mi)
            #pragma unroll
            for (int ni = 0; ni < 4; ++ni)
                acc[mi][ni] = __builtin_amdgcn_mfma_f32_16x16x32_bf16(af[mi], bf[ni], acc[mi][ni], 0, 0, 0);
    }
    #pragma unroll
    for (int mi = 0; mi < 4; ++mi)
        #pragma unroll
        for (int ni = 0; ni < 4; ++ni) {
            int col = n0 + ni * 16 + l16;
            int rowb = r0 + mi * 16 + hi * 4;
            #pragma unroll
            for (int r = 0; r < 4; ++r)
                C[(size_t)(rowb + r) * 256 + col] = f2b(acc[mi][ni][r]);
        }
}

// ---------------- attention pass 1: per-chunk exp-sums + PV partials ----------------
__global__ __launch_bounds__(512) void attn_p1(const u16* __restrict__ qb,
        const u16* __restrict__ kb, const u16* __restrict__ vT,
        float* __restrict__ den, float* __restrict__ o_part)
{
    const int bid = blockIdx.x;
    const int b = bid >> 6, h = (bid >> 3) & 7, chunk = bid & 7;
    const int t = threadIdx.x, w = t >> 6, lane = t & 63;
    const int l16 = lane & 15, hi = lane >> 4;

    __shared__ u16 p_lds[8][16][48];

    s16x8 qf = *(const s16x8*)(qb + ((size_t)(b * 128 + w * 16 + l16)) * 256 + h * 32 + hi * 8);
    const u16* kbase = kb + (size_t)b * 4096 * 256 + h * 32 + hi * 8;
    const u16* vbase = vT + (size_t)(b * 8 + h) * 131072 + hi * 8;

    float dacc[4] = {0, 0, 0, 0};
    f32x4 zero = {0, 0, 0, 0};
    f32x4 oacc[2]; oacc[0] = zero; oacc[1] = zero;

    const int sbeg = chunk * 512, send = sbeg + 512;
    s16x8 kf0 = *(const s16x8*)(kbase + (size_t)(sbeg + l16) * 256);
    s16x8 kf1 = *(const s16x8*)(kbase + (size_t)(sbeg + 16 + l16) * 256);
    s16x8 vf0 = *(const s16x8*)(vbase + (sbeg >> 6) * 2048 + l16 * 64 + (sbeg & 63));
    s16x8 vf1 = *(const s16x8*)(vbase + (sbeg >> 6) * 2048 + (16 + l16) * 64 + (sbeg & 63));

    for (int s0 = sbeg; s0 < send; s0 += 32) {
        s16x8 k0 = kf0, k1 = kf1, v0 = vf0, v1 = vf1;
        int sn = s0 + 32;
        if (sn < send) {
            kf0 = *(const s16x8*)(kbase + (size_t)(sn + l16) * 256);
            kf1 = *(const s16x8*)(kbase + (size_t)(sn + 16 + l16) * 256);
            vf0 = *(const s16x8*)(vbase + (sn >> 6) * 2048 + l16 * 64 + (sn & 63));
            vf1 = *(const s16x8*)(vbase + (sn >> 6) * 2048 + (16 + l16) * 64 + (sn & 63));
        }
        f32x4 lg0 = __builtin_amdgcn_mfma_f32_16x16x32_bf16(qf, k0, zero, 0, 0, 0);
        f32x4 lg1 = __builtin_amdgcn_mfma_f32_16x16x32_bf16(qf, k1, zero, 0, 0, 0);
        #pragma unroll
        for (int r = 0; r < 4; ++r) {
            float e0 = exp2f(lg0[r]);
            float e1 = exp2f(lg1[r]);
            dacc[r] += e0 + e1;
            p_lds[w][hi * 4 + r][l16] = f2b(e0);
            p_lds[w][hi * 4 + r][16 + l16] = f2b(e1);
        }
        s16x8 pf = *(const s16x8*)(&p_lds[w][l16][hi * 8]);
        oacc[0] = __builtin_amdgcn_mfma_f32_16x16x32_bf16(pf, v0, oacc[0], 0, 0, 0);
        oacc[1] = __builtin_amdgcn_mfma_f32_16x16x32_bf16(pf, v1, oacc[1], 0, 0, 0);
    }

    #pragma unroll
    for (int m = 1; m <= 8; m <<= 1) {
        #pragma unroll
        for (int r = 0; r < 4; ++r) dacc[r] += __shfl_xor(dacc[r], m);
    }
    if (l16 == 0) {
        #pragma unroll
        for (int r = 0; r < 4; ++r)
            den[(size_t)chunk * 32768 + (b * 8 + h) * 128 + w * 16 + hi * 4 + r] = dacc[r];
    }
    #pragma unroll
    for (int vi = 0; vi < 2; ++vi)
        #pragma unroll
        for (int r = 0; r < 4; ++r) {
            int mg = w * 16 + hi * 4 + r;
            o_part[(size_t)chunk * 1048576 + (size_t)(b * 128 + mg) * 256 + h * 32 + vi * 16 + l16] = oacc[vi][r];
        }
}

// ---------------- norm: reduce o_part + inline den reduce -> ob ----------------
__global__ __launch_bounds__(256) void norm_k(const float* __restrict__ o_part,
        const float* __restrict__ den, u16* __restrict__ ob)
{
    int idx4 = blockIdx.x * 256 + threadIdx.x;     // B*128*64 = 262144
    int row = idx4 >> 6;
    int col4 = (idx4 & 63) * 4;
    int b = row >> 7, m = row & 127, h = col4 >> 5;
    f32x4 s = {0, 0, 0, 0};
    #pragma unroll
    for (int c = 0; c < 8; ++c)
        s += *(const f32x4*)(o_part + (size_t)c * 1048576 + (size_t)row * 256 + col4);
    float ds = 0;
    int di = (b * 8 + h) * 128 + m;
    #pragma unroll
    for (int c = 0; c < 8; ++c) ds += den[(size_t)c * 32768 + di];
    float rinv = 1.0f / ds;
    ushort4 o;
    o.x = f2b(s[0] * rinv); o.y = f2b(s[1] * rinv);
    o.z = f2b(s[2] * rinv); o.w = f2b(s[3] * rinv);
    *(ushort4*)(ob + (size_t)row * 256 + col4) = o;
}

// ---------------- attention pass 2: prefetched recompute + write attn_g ----------------
__global__ __launch_bounds__(512) void attn_p2(const u16* __restrict__ qb,
        const u16* __restrict__ kb, const float* __restrict__ den,
        float* __restrict__ attn_out)
{
    const int bid = blockIdx.x;                   // b*64 + h*8 + chunk
    const int b = bid >> 6, h = (bid >> 3) & 7, chunk = bid & 7;
    const int t = threadIdx.x, w = t >> 6, lane = t & 63;
    const int l16 = lane & 15, hi = lane >> 4;

    __shared__ float buf[8][16][36];

    s16x8 qf = *(const s16x8*)(qb + ((size_t)(b * 128 + w * 16 + l16)) * 256 + h * 32 + hi * 8);
    const u16* kbase = kb + (size_t)b * 4096 * 256 + h * 32 + hi * 8;

    float rinv[4];
    #pragma unroll
    for (int r = 0; r < 4; ++r) {
        int di = (b * 8 + h) * 128 + w * 16 + hi * 4 + r;
        float ds = 0;
        #pragma unroll
        for (int c = 0; c < 8; ++c) ds += den[(size_t)c * 32768 + di];
        rinv[r] = 1.0f / ds;
    }

    f32x4 zero = {0, 0, 0, 0};
    float* ab = attn_out + (size_t)(b * 8 + h) * 127 * 4096;
    const int srow = lane >> 3;          // 0..7
    const int scol = (lane & 7) * 4;     // 0..28

    const int sbeg = chunk * 512, send = sbeg + 512;
    s16x8 kf0 = *(const s16x8*)(kbase + (size_t)(sbeg + l16) * 256);
    s16x8 kf1 = *(const s16x8*)(kbase + (size_t)(sbeg + 16 + l16) * 256);

    for (int s0 = sbeg; s0 < send; s0 += 32) {
        s16x8 c0 = kf0, c1 = kf1;
        int sn = s0 + 32;
        if (sn < send) {
            kf0 = *(const s16x8*)(kbase + (size_t)(sn + l16) * 256);
            kf1 = *(const s16x8*)(kbase + (size_t)(sn + 16 + l16) * 256);
        }
        f32x4 lg0 = __builtin_amdgcn_mfma_f32_16x16x32_bf16(qf, c0, zero, 0, 0, 0);
        f32x4 lg1 = __builtin_amdgcn_mfma_f32_16x16x32_bf16(qf, c1, zero, 0, 0, 0);
        #pragma unroll
        for (int r = 0; r < 4; ++r) {
            buf[w][hi * 4 + r][l16]      = exp2f(lg0[r]) * rinv[r];
            buf[w][hi * 4 + r][16 + l16] = exp2f(lg1[r]) * rinv[r];
        }
        #pragma unroll
        for (int rb = 0; rb < 2; ++rb) {
            int row = rb * 8 + srow;
            int mg = w * 16 + row;
            f32x4 v = *(const f32x4*)&buf[w][row][scol];
            if (mg < 127)
                *(f32x4*)(ab + (size_t)mg * 4096 + s0 + scol) = v;
        }
    }
}

// ---------------- gemm_lnhh: Hb = LN(ob@Wo^T + Q(csum)) ----------------
__global__ __launch_bounds__(256) void gemm_lnhh(const u16* __restrict__ A,
        const u16* __restrict__ W, const float* __restrict__ csum,
        const float* __restrict__ a_ws, const float* __restrict__ c_ws,
        u16* __restrict__ Hb)
{
    __shared__ __align__(16) char sm[67584];
    __shared__ float aa[256], cc2[256];
    float (*Cs)[264] = (float(*)[264])sm;
    const int t = threadIdx.x;
    const int r0 = blockIdx.x * 64;
    const int lane = t & 63, w = t >> 6;
    const int l16 = lane & 15, hi = lane >> 4;

    aa[t] = a_ws[t] * 0.015625f;
    cc2[t] = c_ws[t];

    const u16* Ag = A + (size_t)r0 * 256;
    #pragma unroll
    for (int i = 0; i < 8; ++i) {
        int c = t + i * 256;
        int row = c >> 5, c16 = c & 31;
        s16x8 v = *(const s16x8*)(Ag + row * 256 + c16 * 8);
        int boff = (c16 * 16) ^ ((row & 7) << 4);
        *(s16x8*)(sm + row * 512 + boff) = v;
    }
    __syncthreads();

    const int n0 = w * 64;
    f32x4 zero = {0, 0, 0, 0};
    f32x4 acc[4][4];
    #pragma unroll
    for (int mi = 0; mi < 4; ++mi)
        #pragma unroll
        for (int ni = 0; ni < 4; ++ni) acc[mi][ni] = zero;
    #pragma unroll
    for (int kk = 0; kk < 8; ++kk) {
        s16x8 af[4], bf[4];
        #pragma unroll
        for (int mi = 0; mi < 4; ++mi) {
            int row = mi * 16 + l16;
            int boff = (kk * 64 + hi * 16) ^ ((row & 7) << 4);
            af[mi] = *(const s16x8*)(sm + row * 512 + boff);
        }
        #pragma unroll
        for (int ni = 0; ni < 4; ++ni)
            bf[ni] = *(const s16x8*)(W + (n0 + ni * 16 + l16) * 256 + kk * 32 + hi * 8);
        #pragma unroll
        for (int mi = 0; mi < 4; ++mi)
            #pragma unroll
            for (int ni = 0; ni < 4; ++ni)
                acc[mi][ni] = __builtin_amdgcn_mfma_f32_16x16x32_bf16(af[mi], bf[ni], acc[mi][ni], 0, 0, 0);
    }
    __syncthreads();
    #pragma unroll
    for (int mi = 0; mi < 4; ++mi)
        #pragma unroll
        for (int ni = 0; ni < 4; ++ni) {
            int col = n0 + ni * 16 + l16;
            int rowb = mi * 16 + hi * 4;
            #pragma unroll
            for (int r = 0; r < 4; ++r)
                Cs[rowb + r][col] = acc[mi][ni][r];
        }
    __syncthreads();
    for (int pass = 0; pass < 16; ++pass) {
        int row = pass * 4 + w;
        int g = r0 + row, mm = g & 127;
        float v[4];
        #pragma unroll
        for (int j = 0; j < 4; ++j) {
            int d = lane + j * 64;
            float qv = 0.0f;
            if (mm != 127)
                qv = (csum[(size_t)g * 256 + d] + csum[(size_t)(g + 1) * 256 + d]) * aa[d] + cc2[d];
            v[j] = Cs[row][d] + qv;
        }
        float s = v[0] + v[1] + v[2] + v[3];
        for (int m = 32; m; m >>= 1) s += __shfl_xor(s, m);
        float mean = s * (1.0f / 256.0f);
        float q = 0;
        #pragma unroll
        for (int j = 0; j < 4; ++j) { float d_ = v[j] - mean; q += d_ * d_; }
        for (int m = 32; m; m >>= 1) q += __shfl_xor(q, m);
        float rs = rsqrtf(q * (1.0f / 256.0f) + 1e-5f);
        #pragma unroll
        for (int j = 0; j < 4; ++j)
            Hb[(size_t)g * 256 + lane + j * 64] = f2b((v[j] - mean) * rs);
    }
}

// ---------------- decoder attention ----------------
__global__ __launch_bounds__(256) void dec_attn_k(const float* __restrict__ q2,
        const u16* __restrict__ k2b, const u16* __restrict__ v2b,
        float* __restrict__ attn_d, u16* __restrict__ o2b)
{
    __shared__ float qs2[24 * 32];
    __shared__ float ks[128][33];
    __shared__ float vs[128][33];
    __shared__ float lg2[24 * 128];
    __shared__ float sinv[24];
    int bid = blockIdx.x, b = bid >> 3, h = bid & 7;
    int t = threadIdx.x;
    const float scale = 0.17677669529663687f;
    for (int idx = t; idx < 4096; idx += 256) {
        int row = idx >> 5, c = idx & 31;
        ks[row][c] = b2f(k2b[((size_t)(b * 128 + row)) * 256 + h * 32 + c]);
        vs[row][c] = b2f(v2b[((size_t)(b * 128 + row)) * 256 + h * 32 + c]);
    }
    for (int idx = t; idx < 768; idx += 256) {
        int p = idx >> 5, i = idx & 31;
        qs2[idx] = q2[p * 256 + h * 32 + i];
    }
    __syncthreads();
    for (int idx = t; idx < 3048; idx += 256) {
        int p = idx / 127, m = idx - p * 127;
        float s = 0;
        #pragma unroll 8
        for (int i = 0; i < 32; ++i) s += qs2[p * 32 + i] * ks[m][i];
        lg2[p * 128 + m] = __expf(s * scale);
    }
    __syncthreads();
    if (t < 24) {
        float s = 0;
        for (int m = 0; m < 127; ++m) s += lg2[t * 128 + m];
        sinv[t] = 1.0f / s;
    }
    __syncthreads();
    float* ad = attn_d + (size_t)bid * 24 * 127;
    for (int idx = t; idx < 3048; idx += 256) {
        int p = idx / 127, m = idx - p * 127;
        float av = lg2[p * 128 + m] * sinv[p];
        lg2[p * 128 + m] = av;
        ad[idx] = av;
    }
    __syncthreads();
    for (int idx = t; idx < 768; idx += 256) {
        int p = idx >> 5, dh = idx & 31;
        float s = 0;
        for (int m = 0; m < 127; ++m)
            s += lg2[p * 128 + m] * vs[m][dh];
        o2b[((size_t)(b * 24 + p)) * 256 + h * 32 + dh] = f2b(s);
    }
}

// ---------------- gemm_ln3: z2 = LN(o2b@Wo2^T + Qd) -> z2f + z2b ----------------
__global__ __launch_bounds__(256) void gemm_ln3(const u16* __restrict__ A,
        const u16* __restrict__ W, const float* __restrict__ dec_Qd,
        float* __restrict__ z2f, u16* __restrict__ z2b)
{
    __shared__ __align__(16) char sm[67584];
    float (*Cs)[264] = (float(*)[264])sm;
    const int t = threadIdx.x;
    const int r0 = blockIdx.x * 64;
    const int lane = t & 63, w = t >> 6;
    const int l16 = lane & 15, hi = lane >> 4;

    const u16* Ag = A + (size_t)r0 * 256;
    #pragma unroll
    for (int i = 0; i < 8; ++i) {
        int c = t + i * 256;
        int row = c >> 5, c16 = c & 31;
        s16x8 v = *(const s16x8*)(Ag + row * 256 + c16 * 8);
        int boff = (c16 * 16) ^ ((row & 7) << 4);
        *(s16x8*)(sm + row * 512 + boff) = v;
    }
    __syncthreads();

    const int n0 = w * 64;
    f32x4 zero = {0, 0, 0, 0};
    f32x4 acc[4][4];
    #pragma unroll
    for (int mi = 0; mi < 4; ++mi)
        #pragma unroll
        for (int ni = 0; ni < 4; ++ni) acc[mi][ni] = zero;
    #pragma unroll
    for (int kk = 0; kk < 8; ++kk) {
        s16x8 af[4], bf[4];
        #pragma unroll
        for (int mi = 0; mi < 4; ++mi) {
            int row = mi * 16 + l16;
            int boff = (kk * 64 + hi * 16) ^ ((row & 7) << 4);
            af[mi] = *(const s16x8*)(sm + row * 512 + boff);
        }
        #pragma unroll
        for (int ni = 0; ni < 4; ++ni)
            bf[ni] = *(const s16x8*)(W + (n0 + ni * 16 + l16) * 256 + kk * 32 + hi * 8);
        #pragma unroll
        for (int mi = 0; mi < 4; ++mi)
            #pragma unroll
            for (int ni = 0; ni < 4; ++ni)
                acc[mi][ni] = __builtin_amdgcn_mfma_f32_16x16x32_bf16(af[mi], bf[ni], acc[mi][ni], 0, 0, 0);
    }
    __syncthreads();
    #pragma unroll
    for (int mi = 0; mi < 4; ++mi)
        #pragma unroll
        for (int ni = 0; ni < 4; ++ni) {
            int col = n0 + ni * 16 + l16;
            int rowb = mi * 16 + hi * 4;
            #pragma unroll
            for (int r = 0; r < 4; ++r)
                Cs[rowb + r][col] = acc[mi][ni][r];
        }
    __syncthreads();
    for (int pass = 0; pass < 16; ++pass) {
        int row = pass * 4 + w;
        int g = r0 + row, p = g % 24;
        float v[4];
        #pragma unroll
        for (int j = 0; j < 4; ++j) {
            int d = lane + j * 64;
            v[j] = Cs[row][d] + dec_Qd[p * 256 + d];
        }
        float s = v[0] + v[1] + v[2] + v[3];
        for (int m = 32; m; m >>= 1) s += __shfl_xor(s, m);
        float mean = s * (1.0f / 256.0f);
        float q = 0;
        #pragma unroll
        for (int j = 0; j < 4; ++j) { float d_ = v[j] - mean; q += d_ * d_; }
        for (int m = 32; m; m >>= 1) q += __shfl_xor(q, m);
        float rs = rsqrtf(q * (1.0f / 256.0f) + 1e-5f);
        #pragma unroll
        for (int j = 0; j < 4; ++j) {
            float u = (v[j] - mean) * rs;
            z2f[(size_t)g * 256 + lane + j * 64] = u;
            z2b[(size_t)g * 256 + lane + j * 64] = f2b(u);
        }
    }
}

// ---------------- gemm_ln5: u = LN(u1b@ff2^T + b2 + z2f); y = coef*(u.out_w + out_b) ----------------
__global__ __launch_bounds__(256) void gemm_ln5(const u16* __restrict__ A,
        const u16* __restrict__ W, const float* __restrict__ bias,
        const float* __restrict__ z2f, const float* __restrict__ out_w,
        const float* __restrict__ out_b, const float* __restrict__ coef,
        float* __restrict__ y)
{
    __shared__ __align__(16) char sm[67584];
    float (*Cs)[264] = (float(*)[264])sm;
    const int t = threadIdx.x;
    const int r0 = blockIdx.x * 64;
    const int lane = t & 63, w = t >> 6;
    const int l16 = lane & 15, hi = lane >> 4;
    const int K = 512;

    const u16* Ag = A + (size_t)r0 * K;
    const int n0 = w * 64;
    f32x4 zero = {0, 0, 0, 0};
    f32x4 acc[4][4];
    #pragma unroll
    for (int mi = 0; mi < 4; ++mi)
        #pragma unroll
        for (int ni = 0; ni < 4; ++ni) acc[mi][ni] = zero;

    for (int kc = 0; kc < K; kc += 256) {
        if (kc) __syncthreads();
        #pragma unroll
        for (int i = 0; i < 8; ++i) {
            int c = t + i * 256;
            int row = c >> 5, c16 = c & 31;
            s16x8 v = *(const s16x8*)(Ag + (size_t)row * K + kc + c16 * 8);
            int boff = (c16 * 16) ^ ((row & 7) << 4);
            *(s16x8*)(sm + row * 512 + boff) = v;
        }
        __syncthreads();
        #pragma unroll
        for (int kk = 0; kk < 8; ++kk) {
            s16x8 af[4], bf[4];
            #pragma unroll
            for (int mi = 0; mi < 4; ++mi) {
                int row = mi * 16 + l16;
                int boff = (kk * 64 + hi * 16) ^ ((row & 7) << 4);
                af[mi] = *(const s16x8*)(sm + row * 512 + boff);
            }
            #pragma unroll
            for (int ni = 0; ni < 4; ++ni)
                bf[ni] = *(const s16x8*)(W + (size_t)(n0 + ni * 16 + l16) * K + kc + kk * 32 + hi * 8);
            #pragma unroll
            for (int mi = 0; mi < 4; ++mi)
                #pragma unroll
                for (int ni = 0; ni < 4; ++ni)
                    acc[mi][ni] = __builtin_amdgcn_mfma_f32_16x16x32_bf16(af[mi], bf[ni], acc[mi][ni], 0, 0, 0);
        }
    }
    __syncthreads();
    #pragma unroll
    for (int mi = 0; mi < 4; ++mi)
        #pragma unroll
        for (int ni = 0; ni < 4; ++ni) {
            int col = n0 + ni * 16 + l16;
            int rowb = mi * 16 + hi * 4;
            #pragma unroll
            for (int r = 0; r < 4; ++r)
                Cs[rowb + r][col] = acc[mi][ni][r];
        }
    __syncthreads();
    for (int pass = 0; pass < 16; ++pass) {
        int row = pass * 4 + w;
        int g = r0 + row, p = g % 24;
        float v[4];
        #pragma unroll
        for (int j = 0; j < 4; ++j) {
            int d = lane + j * 64;
            v[j] = Cs[row][d] + bias[d] + z2f[(size_t)g * 256 + d];
        }
        float s = v[0] + v[1] + v[2] + v[3];
        for (int m = 32; m; m >>= 1) s += __shfl_xor(s, m);
        float mean = s * (1.0f / 256.0f);
        float q = 0;
        #pragma unroll
        for (int j = 0; j < 4; ++j) { float d_ = v[j] - mean; q += d_ * d_; }
        for (int m = 32; m; m >>= 1) q += __shfl_xor(q, m);
        float rs = rsqrtf(q * (1.0f / 256.0f) + 1e-5f);
        float yp = 0;
        #pragma unroll
        for (int j = 0; j < 4; ++j)
            yp += (v[j] - mean) * rs * out_w[lane + j * 64];
        for (int m = 32; m; m >>= 1) yp += __shfl_xor(yp, m);
        if (lane == 0)
            y[g] = coef[p] * (yp + out_b[0]);
    }
}

extern "C" void kernel_launch(void* const* d_in, const int* in_sizes, int n_in,
                              void* d_out, int out_size, void* d_ws, size_t ws_size,
                              hipStream_t stream)
{
    const float* x        = (const float*)d_in[0];
    const float* dw_w     = (const float*)d_in[2];
    const float* pw_w     = (const float*)d_in[3];
    const float* bn_g     = (const float*)d_in[4];
    const float* bn_b     = (const float*)d_in[5];
    const float* lg_Wq    = (const float*)d_in[6];
    const float* lg_Wk    = (const float*)d_in[7];
    const float* lg_Wv    = (const float*)d_in[8];
    const float* lg_Wo    = (const float*)d_in[9];
    const float* dec_Qd   = (const float*)d_in[10];
    const float* dec_Wq   = (const float*)d_in[11];
    const float* dec_Wk   = (const float*)d_in[12];
    const float* dec_Wv   = (const float*)d_in[13];
    const float* dec_Wo   = (const float*)d_in[14];
    const float* ff1_w    = (const float*)d_in[15];
    const float* ff1_b    = (const float*)d_in[16];
    const float* ff2_w    = (const float*)d_in[17];
    const float* ff2_b    = (const float*)d_in[18];
    const float* out_w    = (const float*)d_in[19];
    const float* out_b    = (const float*)d_in[20];
    const float* gate_lg  = (const float*)d_in[21];

    char* ws = (char*)d_ws;
    size_t off = 0;
    auto alloc = [&](size_t bytes) -> void* {
        void* p = ws + off;
        off = (off + bytes + 255) & ~(size_t)255;
        return p;
    };
    u16*   zp    = (u16*)  alloc(67108864);   // [B*S,256] bf16 post-gelu
    u16*   kb    = (u16*)  alloc(67108864);   // K [B*S,256] bf16
    u16*   vT    = (u16*)  alloc(67108864);   // V blocked [b*8+h][sblk][dh][64] bf16
    float* csum  = (float*)alloc(4194304);
    float* csum2 = (float*)alloc(4194304);
    u16*   qb    = (u16*)  alloc(2097152);
    u16*   ob    = (u16*)  alloc(2097152);
    u16*   Hb    = (u16*)  alloc(2097152);
    u16*   k2b   = (u16*)  alloc(2097152);
    u16*   v2b   = (u16*)  alloc(2097152);
    float* o_part= (float*)alloc(33554432);   // [8][B*128,256]
    float* den   = (float*)alloc(1048576);    // [8][B*H*128]
    u16*   o2b   = (u16*)  alloc(393216);
    float* z2f   = (float*)alloc(786432);
    u16*   z2b   = (u16*)  alloc(393216);
    u16*   u1b   = (u16*)  alloc(786432);
    float* q2    = (float*)alloc(24576);
    float* statp = (float*)alloc(131072);
    float* a_ws  = (float*)alloc(1024);
    float* c_ws  = (float*)alloc(1024);
    float* betak = (float*)alloc(1024);
    float* betav = (float*)alloc(1024);
    float* coef  = (float*)alloc(256);
    u16*   pwb   = (u16*)  alloc(16384);
    u16*   Wk_b  = (u16*)  alloc(131072);
    u16*   Wv_b  = (u16*)  alloc(131072);
    u16*   Wq_b  = (u16*)  alloc(131072);
    u16*   Wo_b  = (u16*)  alloc(131072);
    u16*   Wk2_b = (u16*)  alloc(131072);
    u16*   Wv2_b = (u16*)  alloc(131072);
    u16*   Wo2b  = (u16*)  alloc(131072);
    u16*   ff1b  = (u16*)  alloc(262144);
    u16*   ff2b  = (u16*)  alloc(262144);

    float* y_out  = (float*)d_out;
    float* attn_g = y_out + 768;
    float* attn_d = attn_g + (size_t)32 * 8 * 127 * 4096;

    prep0_k<<<2336, 256, 0, stream>>>(pw_w, lg_Wq, lg_Wo, dec_Wk, dec_Wv, dec_Wo, ff1_w, ff2_w,
                                      pwb, Wq_b, Wo_b, Wk2_b, Wv2_b, Wo2b, ff1b, ff2b);
    dwpw_k<<<2048, 256, 0, stream>>>(x, dw_w, pwb, zp, csum, csum2);
    stats2_k<<<64, 256, 0, stream>>>(csum, csum2, statp);
    prep1_k<<<1, 256, 0, stream>>>(statp, bn_g, bn_b, gate_lg, a_ws, c_ws, coef);
    prepx_k<<<592, 256, 0, stream>>>(lg_Wk, lg_Wv, a_ws, c_ws, dec_Qd, dec_Wq, csum, Wq_b,
                                     Wk_b, Wv_b, betak, betav, q2, qb);
    kv_k<<<2048, 256, 0, stream>>>(zp, Wk_b, Wv_b, betak, betav, kb, vT);
    attn_p1<<<2048, 512, 0, stream>>>(qb, kb, vT, den, o_part);
    norm_k<<<1024, 256, 0, stream>>>(o_part, den, ob);
    attn_p2<<<2048, 512, 0, stream>>>(qb, kb, den, attn_g);
    gemm_lnhh<<<64, 256, 0, stream>>>(ob, Wo_b, csum, a_ws, c_ws, Hb);
    gemm_dual<<<128, 256, 0, stream>>>(Hb, Wk2_b, Wv2_b, k2b, v2b);
    dec_attn_k<<<256, 256, 0, stream>>>(q2, k2b, v2b, attn_d, o2b);
    gemm_ln3<<<12, 256, 0, stream>>>(o2b, Wo2b, dec_Qd, z2f, z2b);
    gemm_g<2><<<24, 256, 0, stream>>>(z2b, ff1b, ff1_b, u1b, 256, 2);
    gemm_ln5<<<12, 256, 0, stream>>>(u1b, ff2b, ff2_b, z2f, out_w, out_b, coef, y_out);
}

// Round 13
// 553.929 us; speedup vs baseline: 1.1112x; 1.0832x over previous
//
#include <hip/hip_runtime.h>
#include <hip/hip_bf16.h>
#include <cmath>

typedef unsigned short u16;
typedef __attribute__((ext_vector_type(4))) float f32x4;
typedef __attribute__((ext_vector_type(8))) short s16x8;

__device__ __forceinline__ float b2f(u16 u) { return __uint_as_float(((unsigned)u) << 16); }
__device__ __forceinline__ u16 f2b(float f) {
    unsigned u = __float_as_uint(f);
    unsigned r = (u + 0x7fffu + ((u >> 16) & 1u)) >> 16;
    return (u16)r;
}
__device__ __forceinline__ float gelu_f(float x) {
    return 0.5f * x * (1.0f + erff(x * 0.70710678118654752f));
}

#define FOLD 0.25503590f   // (1/sqrt(32)) * log2(e)

// ---------------- prep0: cast weights to bf16 ----------------
__global__ __launch_bounds__(256) void prep0_k(const float* __restrict__ pw_w,
        const float* __restrict__ lg_Wq, const float* __restrict__ lg_Wo,
        const float* __restrict__ dec_Wk, const float* __restrict__ dec_Wv,
        const float* __restrict__ dec_Wo, const float* __restrict__ ff1_w,
        const float* __restrict__ ff2_w,
        u16* __restrict__ pwb, u16* __restrict__ Wq_b, u16* __restrict__ Wo_b,
        u16* __restrict__ Wk2_b, u16* __restrict__ Wv2_b, u16* __restrict__ Wo2b,
        u16* __restrict__ ff1b, u16* __restrict__ ff2b)
{
    int idx = blockIdx.x * 256 + threadIdx.x;     // 598016 total
    if (idx < 327680) {
        int which = idx >> 16, r = idx & 65535;
        const float* srcs[5] = {lg_Wq, lg_Wo, dec_Wk, dec_Wv, dec_Wo};
        u16* dsts[5] = {Wq_b, Wo_b, Wk2_b, Wv2_b, Wo2b};
        dsts[which][r] = f2b(srcs[which][r]);
    } else if (idx < 458752) {
        int r = idx - 327680;
        ff1b[r] = f2b(ff1_w[r]);
    } else if (idx < 589824) {
        int r = idx - 458752;
        ff2b[r] = f2b(ff2_w[r]);
    } else {
        int r = idx - 589824;
        pwb[r] = f2b(pw_w[r]);
    }
}

// ---------------- fused frontend: depthwise conv + pointwise MFMA + gelu + stat sums ----------------
__global__ __launch_bounds__(256) void dwpw_k(const float* __restrict__ x,
        const float* __restrict__ dw_w, const u16* __restrict__ pwb,
        u16* __restrict__ zp, float* __restrict__ csum, float* __restrict__ csum2)
{
    __shared__ float xs[68][33];
    __shared__ __align__(16) u16 As[64][40];
    const int t = threadIdx.x;
    const int b = blockIdx.x >> 6, s0 = (blockIdx.x & 63) << 6;
    const int r0 = blockIdx.x * 64;
    const int lane = t & 63, w = t >> 6;
    const int l16 = lane & 15, hi = lane >> 4;

    for (int idx = t; idx < 68 * 32; idx += 256) {
        int row = idx >> 5, c = idx & 31;
        int sg = s0 - 2 + row;
        xs[row][c] = (sg >= 0 && sg < 4096) ? x[((size_t)b * 4096 + sg) * 32 + c] : 0.0f;
    }
    const int cc = t & 31;
    float wv[5];
    #pragma unroll
    for (int k = 0; k < 5; ++k) wv[k] = dw_w[cc * 5 + k];
    __syncthreads();
    #pragma unroll
    for (int i = 0; i < 8; ++i) {
        int sl = (t + i * 256) >> 5;
        float acc = 0;
        #pragma unroll
        for (int k = 0; k < 5; ++k) acc += xs[sl + k][cc] * wv[k];
        As[sl][cc] = f2b(acc);
    }
    __syncthreads();

    const int n0 = w * 64;
    f32x4 zero = {0, 0, 0, 0};
    s16x8 bf[4];
    #pragma unroll
    for (int ni = 0; ni < 4; ++ni)
        bf[ni] = *(const s16x8*)(pwb + (n0 + ni * 16 + l16) * 32 + hi * 8);

    float cl[4] = {0,0,0,0}, ch[4] = {0,0,0,0};
    float ql[4] = {0,0,0,0}, qh[4] = {0,0,0,0};

    #pragma unroll
    for (int mi = 0; mi < 4; ++mi) {
        s16x8 af = *(const s16x8*)&As[mi * 16 + l16][hi * 8];
        #pragma unroll
        for (int ni = 0; ni < 4; ++ni) {
            f32x4 acc = __builtin_amdgcn_mfma_f32_16x16x32_bf16(af, bf[ni], zero, 0, 0, 0);
            int col = n0 + ni * 16 + l16;
            int rowb = r0 + mi * 16 + hi * 4;
            #pragma unroll
            for (int r = 0; r < 4; ++r) {
                float e = gelu_f(acc[r]);
                zp[(size_t)(rowb + r) * 256 + col] = f2b(e);
                if (mi < 2) { cl[ni] += e; ql[ni] += e * e; }
                else        { ch[ni] += e; qh[ni] += e * e; }
            }
        }
    }
    #pragma unroll
    for (int ni = 0; ni < 4; ++ni) {
        #pragma unroll
        for (int m = 16; m <= 32; m <<= 1) {
            cl[ni] += __shfl_xor(cl[ni], m);
            ch[ni] += __shfl_xor(ch[ni], m);
            ql[ni] += __shfl_xor(ql[ni], m);
            qh[ni] += __shfl_xor(qh[ni], m);
        }
        if (lane < 16) {
            int col = n0 + ni * 16 + lane;
            size_t bc = (size_t)(r0 >> 5);
            csum [bc * 256 + col]       = cl[ni];
            csum [(bc + 1) * 256 + col] = ch[ni];
            csum2[bc * 256 + col]       = ql[ni];
            csum2[(bc + 1) * 256 + col] = qh[ni];
        }
    }
}

// ---------------- stats2: reduce csum/csum2 over chunks -> statp[64][512] ----------------
__global__ __launch_bounds__(256) void stats2_k(const float* __restrict__ csum,
        const float* __restrict__ csum2, float* __restrict__ statp)
{
    int j = blockIdx.x, t = threadIdx.x;
    float s1 = 0, s2 = 0;
    for (int i = 0; i < 64; ++i) {
        s1 += csum [(size_t)(j * 64 + i) * 256 + t];
        s2 += csum2[(size_t)(j * 64 + i) * 256 + t];
    }
    statp[j * 512 + t] = s1;
    statp[j * 512 + 256 + t] = s2;
}

// ---------------- prep1: BN affine + gate coef ----------------
__global__ __launch_bounds__(256) void prep1_k(const float* __restrict__ statp,
        const float* __restrict__ bn_g, const float* __restrict__ bn_b,
        const float* __restrict__ gate_logits,
        float* __restrict__ a_ws, float* __restrict__ c_ws, float* __restrict__ coef)
{
    int t = threadIdx.x;
    float s1 = 0, s2 = 0;
    for (int j = 0; j < 64; ++j) {
        s1 += statp[j * 512 + t];
        s2 += statp[j * 512 + 256 + t];
    }
    const float invN = 1.0f / 131072.0f;
    float mean = s1 * invN;
    float var = s2 * invN - mean * mean;
    float av = bn_g[t] * rsqrtf(var + 1e-5f);
    a_ws[t] = av;
    c_ws[t] = bn_b[t] - mean * av;
    if (t < 24) {
        float g0 = gate_logits[t * 3], g1 = gate_logits[t * 3 + 1], g2 = gate_logits[t * 3 + 2];
        float mx = fmaxf(g0, fmaxf(g1, g2));
        float e0 = __expf(g0 - mx), e1 = __expf(g1 - mx), e2 = __expf(g2 - mx);
        coef[t] = (e1 + e2) / (e0 + e1 + e2);
    }
}

// ---------------- prep2b: fold Wk/Wv by BN scale + beta reduction ----------------
__global__ __launch_bounds__(256) void prep2b_k(const float* __restrict__ lg_Wk,
        const float* __restrict__ lg_Wv, const float* __restrict__ a_ws,
        const float* __restrict__ c_ws,
        u16* __restrict__ Wk_b, u16* __restrict__ Wv_b,
        float* __restrict__ betak, float* __restrict__ betav)
{
    __shared__ float red[4];
    int bid = blockIdx.x;                 // 512: which*256 + row
    int which = bid >> 8, row = bid & 255, t = threadIdx.x;
    const float* Wsrc = which ? lg_Wv : lg_Wk;
    float wv = Wsrc[row * 256 + t];
    (which ? Wv_b : Wk_b)[row * 256 + t] = f2b(wv * a_ws[t]);
    float v = wv * c_ws[t];
    for (int m = 32; m; m >>= 1) v += __shfl_xor(v, m);
    if ((t & 63) == 0) red[t >> 6] = v;
    __syncthreads();
    if (t == 0) (which ? betav : betak)[row] = red[0] + red[1] + red[2] + red[3];
}

// ---------------- q2 = dec_Qd @ dec_Wq^T (fp32, LDS-staged) ----------------
__global__ __launch_bounds__(256) void q2_k(const float* __restrict__ dec_Qd,
        const float* __restrict__ dec_Wq, float* __restrict__ q2)
{
    __shared__ float wq[16][260];
    __shared__ float qd[24][260];
    int j = blockIdx.x, t = threadIdx.x;   // 16 blocks
    for (int idx = t; idx < 4096; idx += 256) {
        int tl = idx >> 8, d = idx & 255;
        wq[tl][d] = dec_Wq[(j * 16 + tl) * 256 + d];
    }
    for (int idx = t; idx < 6144; idx += 256) {
        int p = idx >> 8, d = idx & 255;
        qd[p][d] = dec_Qd[idx];
    }
    __syncthreads();
    for (int o = t; o < 384; o += 256) {
        int p = o >> 4, tl = o & 15;
        float s = 0;
        #pragma unroll 8
        for (int d = 0; d < 256; ++d) s += qd[p][d] * wq[tl][d];
        q2[p * 256 + j * 16 + tl] = s;
    }
}

// ---------------- qgemm: qb = (win-mean*a + c) @ Wq^T * FOLD, A synthesized from csum ----------------
__global__ __launch_bounds__(256) void qgemm_k(const float* __restrict__ csum,
        const float* __restrict__ a_ws, const float* __restrict__ c_ws,
        const u16* __restrict__ W, u16* __restrict__ qb)
{
    __shared__ u16 As[64 * 256];
    __shared__ float aa[256], ccx[256];
    const int t = threadIdx.x;
    const int r0 = blockIdx.x * 64;
    const int lane = t & 63, w = t >> 6;
    const int l16 = lane & 15, hi = lane >> 4;

    aa[t] = a_ws[t] * 0.015625f;
    ccx[t] = c_ws[t];
    __syncthreads();

    #pragma unroll
    for (int i = 0; i < 8; ++i) {
        int c = t + i * 256;
        int row = c >> 5, c16 = c & 31;
        int g = r0 + row, mm = g & 127;
        u16 tmp[8];
        if (mm == 127) {
            #pragma unroll
            for (int j = 0; j < 8; ++j) tmp[j] = 0;
        } else {
            const float* c0p = csum + (size_t)g * 256 + c16 * 8;
            const float* c1p = c0p + 256;
            #pragma unroll
            for (int j = 0; j < 8; ++j) {
                int d = c16 * 8 + j;
                tmp[j] = f2b((c0p[j] + c1p[j]) * aa[d] + ccx[d]);
            }
        }
        int boff = (c16 * 16) ^ ((row & 7) << 4);
        *(s16x8*)((char*)As + row * 512 + boff) = *(s16x8*)tmp;
    }
    __syncthreads();

    const int n0 = w * 64;
    f32x4 zero = {0, 0, 0, 0};
    f32x4 acc[4][4];
    #pragma unroll
    for (int mi = 0; mi < 4; ++mi)
        #pragma unroll
        for (int ni = 0; ni < 4; ++ni) acc[mi][ni] = zero;

    #pragma unroll
    for (int kk = 0; kk < 8; ++kk) {
        s16x8 af[4], bf[4];
        #pragma unroll
        for (int mi = 0; mi < 4; ++mi) {
            int row = mi * 16 + l16;
            int boff = (kk * 64 + hi * 16) ^ ((row & 7) << 4);
            af[mi] = *(const s16x8*)((const char*)As + row * 512 + boff);
        }
        #pragma unroll
        for (int ni = 0; ni < 4; ++ni)
            bf[ni] = *(const s16x8*)(W + (n0 + ni * 16 + l16) * 256 + kk * 32 + hi * 8);
        #pragma unroll
        for (int mi = 0; mi < 4; ++mi)
            #pragma unroll
            for (int ni = 0; ni < 4; ++ni)
                acc[mi][ni] = __builtin_amdgcn_mfma_f32_16x16x32_bf16(af[mi], bf[ni], acc[mi][ni], 0, 0, 0);
    }

    #pragma unroll
    for (int mi = 0; mi < 4; ++mi)
        #pragma unroll
        for (int ni = 0; ni < 4; ++ni) {
            int col = n0 + ni * 16 + l16;
            int rowb = r0 + mi * 16 + hi * 4;
            #pragma unroll
            for (int r = 0; r < 4; ++r)
                qb[(size_t)(rowb + r) * 256 + col] = f2b(acc[mi][ni][r] * FOLD);
        }
}

// ---------------- fused K/V projection: kb row-major + vT transposed ----------------
__global__ __launch_bounds__(256) void kv_k(const u16* __restrict__ zp,
        const u16* __restrict__ Wk, const u16* __restrict__ Wv,
        const float* __restrict__ betak, const float* __restrict__ betav,
        u16* __restrict__ kb, u16* __restrict__ vT)
{
    __shared__ u16 As[64 * 256];
    const int t = threadIdx.x;
    const int r0 = blockIdx.x * 64;
    const int lane = t & 63, w = t >> 6;
    const int l16 = lane & 15, hi = lane >> 4;

    const u16* Ag = zp + (size_t)r0 * 256;
    #pragma unroll
    for (int i = 0; i < 8; ++i) {
        int c = t + i * 256;
        int row = c >> 5, c16 = c & 31;
        s16x8 v = *(const s16x8*)(Ag + row * 256 + c16 * 8);
        int boff = (c16 * 16) ^ ((row & 7) << 4);
        *(s16x8*)((char*)As + row * 512 + boff) = v;
    }
    __syncthreads();

    const int n0 = w * 64;
    f32x4 zero = {0, 0, 0, 0};
    f32x4 acc[4][4];
    #pragma unroll
    for (int mi = 0; mi < 4; ++mi)
        #pragma unroll
        for (int ni = 0; ni < 4; ++ni) acc[mi][ni] = zero;

    #pragma unroll
    for (int kk = 0; kk < 8; ++kk) {
        s16x8 af[4], bfk[4];
        #pragma unroll
        for (int mi = 0; mi < 4; ++mi) {
            int row = mi * 16 + l16;
            int boff = (kk * 64 + hi * 16) ^ ((row & 7) << 4);
            af[mi] = *(const s16x8*)((const char*)As + row * 512 + boff);
        }
        #pragma unroll
        for (int ni = 0; ni < 4; ++ni)
            bfk[ni] = *(const s16x8*)(Wk + (n0 + ni * 16 + l16) * 256 + kk * 32 + hi * 8);
        #pragma unroll
        for (int mi = 0; mi < 4; ++mi)
            #pragma unroll
            for (int ni = 0; ni < 4; ++ni)
                acc[mi][ni] = __builtin_amdgcn_mfma_f32_16x16x32_bf16(af[mi], bfk[ni], acc[mi][ni], 0, 0, 0);
    }
    #pragma unroll
    for (int mi = 0; mi < 4; ++mi)
        #pragma unroll
        for (int ni = 0; ni < 4; ++ni) {
            int col = n0 + ni * 16 + l16;
            float bv = betak[col];
            int rowb = r0 + mi * 16 + hi * 4;
            #pragma unroll
            for (int r = 0; r < 4; ++r)
                kb[(size_t)(rowb + r) * 256 + col] = f2b(acc[mi][ni][r] + bv);
        }

    #pragma unroll
    for (int mi = 0; mi < 4; ++mi)
        #pragma unroll
        for (int ni = 0; ni < 4; ++ni) acc[mi][ni] = zero;
    #pragma unroll
    for (int kk = 0; kk < 8; ++kk) {
        s16x8 af[4], bfv[4];
        #pragma unroll
        for (int mi = 0; mi < 4; ++mi) {
            int row = mi * 16 + l16;
            int boff = (kk * 64 + hi * 16) ^ ((row & 7) << 4);
            af[mi] = *(const s16x8*)((const char*)As + row * 512 + boff);
        }
        #pragma unroll
        for (int ni = 0; ni < 4; ++ni)
            bfv[ni] = *(const s16x8*)(Wv + (n0 + ni * 16 + l16) * 256 + kk * 32 + hi * 8);
        #pragma unroll
        for (int mi = 0; mi < 4; ++mi)
            #pragma unroll
            for (int ni = 0; ni < 4; ++ni)
                acc[mi][ni] = __builtin_amdgcn_mfma_f32_16x16x32_bf16(af[mi], bfv[ni], acc[mi][ni], 0, 0, 0);
    }
    const int b = r0 >> 12, sbase = r0 & 4095;
    #pragma unroll
    for (int mi = 0; mi < 4; ++mi)
        #pragma unroll
        for (int ni = 0; ni < 4; ++ni) {
            int col = n0 + ni * 16 + l16;
            float bv = betav[col];
            int h = col >> 5, dh = col & 31;
            int s = sbase + mi * 16 + hi * 4;
            ushort4 pk;
            pk.x = f2b(acc[mi][ni][0] + bv);
            pk.y = f2b(acc[mi][ni][1] + bv);
            pk.z = f2b(acc[mi][ni][2] + bv);
            pk.w = f2b(acc[mi][ni][3] + bv);
            *(ushort4*)(vT + ((size_t)((b * 8 + h) * 32 + dh)) * 4096 + s) = pk;
        }
}

// ---------------- generic MFMA GEMM: C[R,N] = A[R,K] @ W^T[N,K] (+bias) ----------------
// MODE 0: bf16 out; MODE 1: f32 out; MODE 2: bf16 gelu(x+bias)
template<int MODE>
__global__ __launch_bounds__(256) void gemm_g(const u16* __restrict__ A,
        const u16* __restrict__ W, const float* __restrict__ bias,
        void* __restrict__ Cout, int K, int ntn)
{
    __shared__ u16 As[64 * 256];
    const int t = threadIdx.x;
    const int rt = blockIdx.x / ntn, nt = blockIdx.x % ntn;
    const int r0 = rt * 64, N = ntn * 256;
    const int lane = t & 63, w = t >> 6;
    const int l16 = lane & 15, hi = lane >> 4;

    const u16* Ag = A + (size_t)r0 * K;
    const int n0 = w * 64;
    f32x4 zero = {0, 0, 0, 0};
    f32x4 acc[4][4];
    #pragma unroll
    for (int mi = 0; mi < 4; ++mi)
        #pragma unroll
        for (int ni = 0; ni < 4; ++ni) acc[mi][ni] = zero;

    for (int kc = 0; kc < K; kc += 256) {
        if (kc) __syncthreads();
        #pragma unroll
        for (int i = 0; i < 8; ++i) {
            int c = t + i * 256;
            int row = c >> 5, c16 = c & 31;
            s16x8 v = *(const s16x8*)(Ag + (size_t)row * K + kc + c16 * 8);
            int boff = (c16 * 16) ^ ((row & 7) << 4);
            *(s16x8*)((char*)As + row * 512 + boff) = v;
        }
        __syncthreads();
        #pragma unroll
        for (int kk = 0; kk < 8; ++kk) {
            s16x8 af[4], bf[4];
            #pragma unroll
            for (int mi = 0; mi < 4; ++mi) {
                int row = mi * 16 + l16;
                int boff = (kk * 64 + hi * 16) ^ ((row & 7) << 4);
                af[mi] = *(const s16x8*)((const char*)As + row * 512 + boff);
            }
            #pragma unroll
            for (int ni = 0; ni < 4; ++ni) {
                int j = nt * 256 + n0 + ni * 16 + l16;
                bf[ni] = *(const s16x8*)(W + (size_t)j * K + kc + kk * 32 + hi * 8);
            }
            #pragma unroll
            for (int mi = 0; mi < 4; ++mi)
                #pragma unroll
                for (int ni = 0; ni < 4; ++ni)
                    acc[mi][ni] = __builtin_amdgcn_mfma_f32_16x16x32_bf16(af[mi], bf[ni], acc[mi][ni], 0, 0, 0);
        }
    }

    #pragma unroll
    for (int mi = 0; mi < 4; ++mi)
        #pragma unroll
        for (int ni = 0; ni < 4; ++ni) {
            int col = nt * 256 + n0 + ni * 16 + l16;
            float bv = bias ? bias[col] : 0.0f;
            int rowb = r0 + mi * 16 + hi * 4;
            #pragma unroll
            for (int r = 0; r < 4; ++r) {
                float v = acc[mi][ni][r] + bv;
                if (MODE == 0)      ((u16*)Cout)[(size_t)(rowb + r) * N + col] = f2b(v);
                else if (MODE == 1) ((float*)Cout)[(size_t)(rowb + r) * N + col] = v;
                else                ((u16*)Cout)[(size_t)(rowb + r) * N + col] = f2b(gelu_f(v));
            }
        }
}

// ---------------- dual 256-K GEMM: Hb -> k2b / v2b in one dispatch ----------------
__global__ __launch_bounds__(256) void gemm_dual(const u16* __restrict__ A,
        const u16* __restrict__ W0, const u16* __restrict__ W1,
        u16* __restrict__ C0, u16* __restrict__ C1)
{
    __shared__ u16 As[64 * 256];
    const int t = threadIdx.x;
    const int which = blockIdx.x >> 6;
    const int r0 = (blockIdx.x & 63) * 64;
    const u16* W = which ? W1 : W0;
    u16* C = which ? C1 : C0;
    const int lane = t & 63, w = t >> 6;
    const int l16 = lane & 15, hi = lane >> 4;

    const u16* Ag = A + (size_t)r0 * 256;
    #pragma unroll
    for (int i = 0; i < 8; ++i) {
        int c = t + i * 256;
        int row = c >> 5, c16 = c & 31;
        s16x8 v = *(const s16x8*)(Ag + row * 256 + c16 * 8);
        int boff = (c16 * 16) ^ ((row & 7) << 4);
        *(s16x8*)((char*)As + row * 512 + boff) = v;
    }
    __syncthreads();

    const int n0 = w * 64;
    f32x4 zero = {0, 0, 0, 0};
    f32x4 acc[4][4];
    #pragma unroll
    for (int mi = 0; mi < 4; ++mi)
        #pragma unroll
        for (int ni = 0; ni < 4; ++ni) acc[mi][ni] = zero;

    #pragma unroll
    for (int kk = 0; kk < 8; ++kk) {
        s16x8 af[4], bf[4];
        #pragma unroll
        for (int mi = 0; mi < 4; ++mi) {
            int row = mi * 16 + l16;
            int boff = (kk * 64 + hi * 16) ^ ((row & 7) << 4);
            af[mi] = *(const s16x8*)((const char*)As + row * 512 + boff);
        }
        #pragma unroll
        for (int ni = 0; ni < 4; ++ni)
            bf[ni] = *(const s16x8*)(W + (n0 + ni * 16 + l16) * 256 + kk * 32 + hi * 8);
        #pragma unroll
        for (int mi = 0; mi < 4; ++mi)
            #pragma unroll
            for (int ni = 0; ni < 4; ++ni)
                acc[mi][ni] = __builtin_amdgcn_mfma_f32_16x16x32_bf16(af[mi], bf[ni], acc[mi][ni], 0, 0, 0);
    }
    #pragma unroll
    for (int mi = 0; mi < 4; ++mi)
        #pragma unroll
        for (int ni = 0; ni < 4; ++ni) {
            int col = n0 + ni * 16 + l16;
            int rowb = r0 + mi * 16 + hi * 4;
            #pragma unroll
            for (int r = 0; r < 4; ++r)
                C[(size_t)(rowb + r) * 256 + col] = f2b(acc[mi][ni][r]);
        }
}

// ---------------- attention pass 1: pipelined per-chunk exp-sums + PV partials ----------------
__global__ __launch_bounds__(512) void attn_p1(const u16* __restrict__ qb,
        const u16* __restrict__ kb, const u16* __restrict__ vT,
        float* __restrict__ den, float* __restrict__ o_part)
{
    const int bid = blockIdx.x;                   // b*64 + h*8 + chunk
    const int b = bid >> 6, h = (bid >> 3) & 7, chunk = bid & 7;
    const int t = threadIdx.x, w = t >> 6, lane = t & 63;
    const int l16 = lane & 15, hi = lane >> 4;

    __shared__ u16 p_lds[8][16][48];

    s16x8 qf = *(const s16x8*)(qb + ((size_t)(b * 128 + w * 16 + l16)) * 256 + h * 32 + hi * 8);
    const u16* kbase = kb + (size_t)b * 4096 * 256 + h * 32 + hi * 8;
    const u16* vbase = vT + ((size_t)(b * 8 + h)) * 32 * 4096 + hi * 8;

    float dacc[4] = {0, 0, 0, 0};
    f32x4 zero = {0, 0, 0, 0};
    f32x4 oacc[2]; oacc[0] = zero; oacc[1] = zero;

    const int sbeg = chunk * 512, send = sbeg + 512;
    s16x8 kf0 = *(const s16x8*)(kbase + (size_t)(sbeg + l16) * 256);
    s16x8 kf1 = *(const s16x8*)(kbase + (size_t)(sbeg + 16 + l16) * 256);
    s16x8 vf0 = *(const s16x8*)(vbase + ((size_t)l16) * 4096 + sbeg);
    s16x8 vf1 = *(const s16x8*)(vbase + ((size_t)(16 + l16)) * 4096 + sbeg);

    for (int s0 = sbeg; s0 < send; s0 += 32) {
        s16x8 k0 = kf0, k1 = kf1, v0 = vf0, v1 = vf1;
        int sn = s0 + 32;
        if (sn < send) {
            kf0 = *(const s16x8*)(kbase + (size_t)(sn + l16) * 256);
            kf1 = *(const s16x8*)(kbase + (size_t)(sn + 16 + l16) * 256);
            vf0 = *(const s16x8*)(vbase + ((size_t)l16) * 4096 + sn);
            vf1 = *(const s16x8*)(vbase + ((size_t)(16 + l16)) * 4096 + sn);
        }
        f32x4 lg0 = __builtin_amdgcn_mfma_f32_16x16x32_bf16(qf, k0, zero, 0, 0, 0);
        f32x4 lg1 = __builtin_amdgcn_mfma_f32_16x16x32_bf16(qf, k1, zero, 0, 0, 0);
        #pragma unroll
        for (int r = 0; r < 4; ++r) {
            float e0 = exp2f(lg0[r]);
            float e1 = exp2f(lg1[r]);
            dacc[r] += e0 + e1;
            p_lds[w][hi * 4 + r][l16] = f2b(e0);
            p_lds[w][hi * 4 + r][16 + l16] = f2b(e1);
        }
        s16x8 pf = *(const s16x8*)(&p_lds[w][l16][hi * 8]);
        oacc[0] = __builtin_amdgcn_mfma_f32_16x16x32_bf16(pf, v0, oacc[0], 0, 0, 0);
        oacc[1] = __builtin_amdgcn_mfma_f32_16x16x32_bf16(pf, v1, oacc[1], 0, 0, 0);
    }

    #pragma unroll
    for (int m = 1; m <= 8; m <<= 1) {
        #pragma unroll
        for (int r = 0; r < 4; ++r) dacc[r] += __shfl_xor(dacc[r], m);
    }
    if (l16 == 0) {
        #pragma unroll
        for (int r = 0; r < 4; ++r)
            den[(size_t)chunk * 32768 + (b * 8 + h) * 128 + w * 16 + hi * 4 + r] = dacc[r];
    }
    #pragma unroll
    for (int vi = 0; vi < 2; ++vi)
        #pragma unroll
        for (int r = 0; r < 4; ++r) {
            int mg = w * 16 + hi * 4 + r;
            o_part[(size_t)chunk * 1048576 + (size_t)(b * 128 + mg) * 256 + h * 32 + vi * 16 + l16] = oacc[vi][r];
        }
}

// ---------------- reduce den over chunks -> 1/den ----------------
__global__ __launch_bounds__(256) void dinv_k(const float* __restrict__ den, float* __restrict__ den_inv)
{
    int i = blockIdx.x * 256 + threadIdx.x;        // 32768
    float s = 0;
    #pragma unroll
    for (int c = 0; c < 8; ++c) s += den[(size_t)c * 32768 + i];
    den_inv[i] = 1.0f / s;
}

// ---------------- reduce o_part, normalize -> ob bf16 ----------------
__global__ __launch_bounds__(256) void norm_k(const float* __restrict__ o_part,
        const float* __restrict__ den_inv, u16* __restrict__ ob)
{
    size_t idx = (size_t)blockIdx.x * 256 + threadIdx.x;   // B*128*256
    int row = (int)(idx >> 8);
    int col = (int)(idx & 255);
    int b = row >> 7, m = row & 127, h = col >> 5;
    float s = 0;
    #pragma unroll
    for (int c = 0; c < 8; ++c) s += o_part[(size_t)c * 1048576 + idx];
    ob[idx] = f2b(s * den_inv[b * 1024 + h * 128 + m]);
}

// ---------------- attention pass 2: recompute, write attn_g ----------------
__global__ __launch_bounds__(512) void attn_p2(const u16* __restrict__ qb,
        const u16* __restrict__ kb, const float* __restrict__ den_inv,
        float* __restrict__ attn_out)
{
    const int bid = blockIdx.x;                   // b*64 + h*8 + chunk
    const int b = bid >> 6, h = (bid >> 3) & 7, chunk = bid & 7;
    const int t = threadIdx.x, w = t >> 6, lane = t & 63;
    const int l16 = lane & 15, hi = lane >> 4;

    __shared__ float buf[8][16][68];

    s16x8 qf = *(const s16x8*)(qb + ((size_t)(b * 128 + w * 16 + l16)) * 256 + h * 32 + hi * 8);
    const u16* kbase = kb + (size_t)b * 4096 * 256 + h * 32 + hi * 8;

    float rinv[4];
    #pragma unroll
    for (int r = 0; r < 4; ++r)
        rinv[r] = den_inv[b * 1024 + h * 128 + w * 16 + hi * 4 + r];

    f32x4 zero = {0, 0, 0, 0};
    float* ab = attn_out + (size_t)(b * 8 + h) * 127 * 4096;
    const int nrow = (w < 7) ? 16 : 15;            // skip pad row m=127

    const int sbeg = chunk * 512, send = sbeg + 512;
    for (int s0 = sbeg; s0 < send; s0 += 64) {
        #pragma unroll
        for (int kk = 0; kk < 4; ++kk) {
            int sg = s0 + kk * 16 + l16;
            s16x8 kf = *(const s16x8*)(kbase + (size_t)sg * 256);
            f32x4 lg = __builtin_amdgcn_mfma_f32_16x16x32_bf16(qf, kf, zero, 0, 0, 0);
            #pragma unroll
            for (int r = 0; r < 4; ++r)
                buf[w][hi * 4 + r][kk * 16 + l16] = exp2f(lg[r]) * rinv[r];
        }
        float* dst = ab + (size_t)(w * 16) * 4096 + s0 + lane;
        for (int r = 0; r < nrow; ++r)
            dst[(size_t)r * 4096] = buf[w][r][lane];
    }
}

// ---------------- Hh = LN(og + Q(csum)) -> bf16 ----------------
__global__ __launch_bounds__(256) void ln_hh(const float* __restrict__ og,
        const float* __restrict__ csum, const float* __restrict__ a_ws,
        const float* __restrict__ c_ws, u16* __restrict__ Hb)
{
    __shared__ float red[8];
    int row = blockIdx.x, t = threadIdx.x;
    int mm = row & 127;
    float qv = 0.0f;
    if (mm != 127)
        qv = (csum[(size_t)row * 256 + t] + csum[(size_t)(row + 1) * 256 + t]) *
             (0.015625f * a_ws[t]) + c_ws[t];
    float v = og[(size_t)row * 256 + t] + qv;
    float s = v;
    for (int m = 32; m; m >>= 1) s += __shfl_xor(s, m);
    if ((t & 63) == 0) red[t >> 6] = s;
    __syncthreads();
    float mean = (red[0] + red[1] + red[2] + red[3]) * (1.0f / 256.0f);
    __syncthreads();
    float d = v - mean;
    float q = d * d;
    for (int m = 32; m; m >>= 1) q += __shfl_xor(q, m);
    if ((t & 63) == 0) red[t >> 6] = q;
    __syncthreads();
    float var = (red[0] + red[1] + red[2] + red[3]) * (1.0f / 256.0f);
    Hb[(size_t)row * 256 + t] = f2b(d * rsqrtf(var + 1e-5f));
}

// ---------------- decoder attention: LDS-staged, attn_d + o2b ----------------
__global__ __launch_bounds__(256) void dec_attn_k(const float* __restrict__ q2,
        const u16* __restrict__ k2b, const u16* __restrict__ v2b,
        float* __restrict__ attn_d, u16* __restrict__ o2b)
{
    __shared__ float qs2[24 * 32];
    __shared__ float ks[128][33];
    __shared__ float vs[128][33];
    __shared__ float lg2[24 * 128];
    __shared__ float sinv[24];
    int bid = blockIdx.x, b = bid >> 3, h = bid & 7;
    int t = threadIdx.x;
    const float scale = 0.17677669529663687f;
    for (int idx = t; idx < 4096; idx += 256) {
        int row = idx >> 5, c = idx & 31;
        ks[row][c] = b2f(k2b[((size_t)(b * 128 + row)) * 256 + h * 32 + c]);
        vs[row][c] = b2f(v2b[((size_t)(b * 128 + row)) * 256 + h * 32 + c]);
    }
    for (int idx = t; idx < 768; idx += 256) {
        int p = idx >> 5, i = idx & 31;
        qs2[idx] = q2[p * 256 + h * 32 + i];
    }
    __syncthreads();
    for (int idx = t; idx < 3048; idx += 256) {
        int p = idx / 127, m = idx - p * 127;
        float s = 0;
        #pragma unroll 8
        for (int i = 0; i < 32; ++i) s += qs2[p * 32 + i] * ks[m][i];
        lg2[p * 128 + m] = __expf(s * scale);
    }
    __syncthreads();
    if (t < 24) {
        float s = 0;
        for (int m = 0; m < 127; ++m) s += lg2[t * 128 + m];
        sinv[t] = 1.0f / s;
    }
    __syncthreads();
    float* ad = attn_d + (size_t)bid * 24 * 127;
    for (int idx = t; idx < 3048; idx += 256) {
        int p = idx / 127, m = idx - p * 127;
        float av = lg2[p * 128 + m] * sinv[p];
        lg2[p * 128 + m] = av;
        ad[idx] = av;
    }
    __syncthreads();
    for (int idx = t; idx < 768; idx += 256) {
        int p = idx >> 5, dh = idx & 31;
        float s = 0;
        for (int m = 0; m < 127; ++m)
            s += lg2[p * 128 + m] * vs[m][dh];
        o2b[((size_t)(b * 24 + p)) * 256 + h * 32 + dh] = f2b(s);
    }
}

// ---------------- ln3: z2 = LN(og2 + Qd) -> f32 + bf16 ----------------
__global__ __launch_bounds__(256) void ln3_k(const float* __restrict__ og2,
        const float* __restrict__ dec_Qd, float* __restrict__ z2f, u16* __restrict__ z2b)
{
    __shared__ float red[8];
    int row = blockIdx.x, p = row % 24, t = threadIdx.x;
    float v = og2[(size_t)row * 256 + t] + dec_Qd[p * 256 + t];
    float s = v;
    for (int m = 32; m; m >>= 1) s += __shfl_xor(s, m);
    if ((t & 63) == 0) red[t >> 6] = s;
    __syncthreads();
    float mean = (red[0] + red[1] + red[2] + red[3]) * (1.0f / 256.0f);
    __syncthreads();
    float d = v - mean, q = d * d;
    for (int m = 32; m; m >>= 1) q += __shfl_xor(q, m);
    if ((t & 63) == 0) red[t >> 6] = q;
    __syncthreads();
    float var = (red[0] + red[1] + red[2] + red[3]) * (1.0f / 256.0f);
    float u = d * rsqrtf(var + 1e-5f);
    z2f[(size_t)row * 256 + t] = u;
    z2b[(size_t)row * 256 + t] = f2b(u);
}

// ---------------- ln5: u = LN(uraw + z2); y = coef*(u.out_w + out_b) ----------------
__global__ __launch_bounds__(256) void ln5_k(const float* __restrict__ uraw,
        const float* __restrict__ z2f, const float* __restrict__ out_w,
        const float* __restrict__ out_b, const float* __restrict__ coef,
        float* __restrict__ y)
{
    __shared__ float red[8];
    int row = blockIdx.x, p = row % 24, t = threadIdx.x;
    float v = uraw[(size_t)row * 256 + t] + z2f[(size_t)row * 256 + t];
    float s = v;
    for (int m = 32; m; m >>= 1) s += __shfl_xor(s, m);
    if ((t & 63) == 0) red[t >> 6] = s;
    __syncthreads();
    float mean = (red[0] + red[1] + red[2] + red[3]) * (1.0f / 256.0f);
    __syncthreads();
    float d = v - mean, q = d * d;
    for (int m = 32; m; m >>= 1) q += __shfl_xor(q, m);
    if ((t & 63) == 0) red[t >> 6] = q;
    __syncthreads();
    float var = (red[0] + red[1] + red[2] + red[3]) * (1.0f / 256.0f);
    float u = d * rsqrtf(var + 1e-5f);
    __syncthreads();
    float yp = u * out_w[t];
    for (int m = 32; m; m >>= 1) yp += __shfl_xor(yp, m);
    if ((t & 63) == 0) red[t >> 6] = yp;
    __syncthreads();
    if (t == 0) {
        float tot = red[0] + red[1] + red[2] + red[3] + out_b[0];
        y[row] = coef[p] * tot;
    }
}

extern "C" void kernel_launch(void* const* d_in, const int* in_sizes, int n_in,
                              void* d_out, int out_size, void* d_ws, size_t ws_size,
                              hipStream_t stream)
{
    const float* x        = (const float*)d_in[0];
    const float* dw_w     = (const float*)d_in[2];
    const float* pw_w     = (const float*)d_in[3];
    const float* bn_g     = (const float*)d_in[4];
    const float* bn_b     = (const float*)d_in[5];
    const float* lg_Wq    = (const float*)d_in[6];
    const float* lg_Wk    = (const float*)d_in[7];
    const float* lg_Wv    = (const float*)d_in[8];
    const float* lg_Wo    = (const float*)d_in[9];
    const float* dec_Qd   = (const float*)d_in[10];
    const float* dec_Wq   = (const float*)d_in[11];
    const float* dec_Wk   = (const float*)d_in[12];
    const float* dec_Wv   = (const float*)d_in[13];
    const float* dec_Wo   = (const float*)d_in[14];
    const float* ff1_w    = (const float*)d_in[15];
    const float* ff1_b    = (const float*)d_in[16];
    const float* ff2_w    = (const float*)d_in[17];
    const float* ff2_b    = (const float*)d_in[18];
    const float* out_w    = (const float*)d_in[19];
    const float* out_b    = (const float*)d_in[20];
    const float* gate_lg  = (const float*)d_in[21];

    char* ws = (char*)d_ws;
    size_t off = 0;
    auto alloc = [&](size_t bytes) -> void* {
        void* p = ws + off;
        off = (off + bytes + 255) & ~(size_t)255;
        return p;
    };
    u16*   zp    = (u16*)  alloc(67108864);   // [B*S,256] bf16 post-gelu
    u16*   kb    = (u16*)  alloc(67108864);   // K [B*S,256] bf16
    u16*   vT    = (u16*)  alloc(67108864);   // V^T [B][H][32][4096] bf16
    float* csum  = (float*)alloc(4194304);    // [4096][256] chunk sums
    float* csum2 = (float*)alloc(4194304);
    u16*   qb    = (u16*)  alloc(2097152);
    u16*   ob    = (u16*)  alloc(2097152);
    float* og    = (float*)alloc(4194304);
    u16*   Hb    = (u16*)  alloc(2097152);
    u16*   k2b   = (u16*)  alloc(2097152);
    u16*   v2b   = (u16*)  alloc(2097152);
    float* o_part= (float*)alloc(33554432);   // [8][B*128,256]
    u16*   o2b   = (u16*)  alloc(393216);
    float* og2   = (float*)alloc(786432);
    float* z2f   = (float*)alloc(786432);
    u16*   z2b   = (u16*)  alloc(393216);
    u16*   u1b   = (u16*)  alloc(786432);
    float* uraw  = (float*)alloc(786432);
    float* q2    = (float*)alloc(24576);
    float* den   = (float*)alloc(1048576);
    float* den_i = (float*)alloc(131072);
    float* statp = (float*)alloc(131072);
    float* a_ws  = (float*)alloc(1024);
    float* c_ws  = (float*)alloc(1024);
    float* betak = (float*)alloc(1024);
    float* betav = (float*)alloc(1024);
    float* coef  = (float*)alloc(256);
    u16*   pwb   = (u16*)  alloc(16384);
    u16*   Wk_b  = (u16*)  alloc(131072);
    u16*   Wv_b  = (u16*)  alloc(131072);
    u16*   Wq_b  = (u16*)  alloc(131072);
    u16*   Wo_b  = (u16*)  alloc(131072);
    u16*   Wk2_b = (u16*)  alloc(131072);
    u16*   Wv2_b = (u16*)  alloc(131072);
    u16*   Wo2b  = (u16*)  alloc(131072);
    u16*   ff1b  = (u16*)  alloc(262144);
    u16*   ff2b  = (u16*)  alloc(262144);

    float* y_out  = (float*)d_out;
    float* attn_g = y_out + 768;
    float* attn_d = attn_g + (size_t)32 * 8 * 127 * 4096;

    prep0_k<<<2336, 256, 0, stream>>>(pw_w, lg_Wq, lg_Wo, dec_Wk, dec_Wv, dec_Wo, ff1_w, ff2_w,
                                      pwb, Wq_b, Wo_b, Wk2_b, Wv2_b, Wo2b, ff1b, ff2b);
    dwpw_k<<<2048, 256, 0, stream>>>(x, dw_w, pwb, zp, csum, csum2);
    stats2_k<<<64, 256, 0, stream>>>(csum, csum2, statp);
    prep1_k<<<1, 256, 0, stream>>>(statp, bn_g, bn_b, gate_lg, a_ws, c_ws, coef);
    prep2b_k<<<512, 256, 0, stream>>>(lg_Wk, lg_Wv, a_ws, c_ws, Wk_b, Wv_b, betak, betav);
    q2_k<<<16, 256, 0, stream>>>(dec_Qd, dec_Wq, q2);
    qgemm_k<<<64, 256, 0, stream>>>(csum, a_ws, c_ws, Wq_b, qb);
    kv_k<<<2048, 256, 0, stream>>>(zp, Wk_b, Wv_b, betak, betav, kb, vT);
    attn_p1<<<2048, 512, 0, stream>>>(qb, kb, vT, den, o_part);
    dinv_k<<<128, 256, 0, stream>>>(den, den_i);
    norm_k<<<4096, 256, 0, stream>>>(o_part, den_i, ob);
    attn_p2<<<2048, 512, 0, stream>>>(qb, kb, den_i, attn_g);
    gemm_g<1><<<64, 256, 0, stream>>>(ob, Wo_b, nullptr, og, 256, 1);
    ln_hh<<<4096, 256, 0, stream>>>(og, csum, a_ws, c_ws, Hb);
    gemm_dual<<<128, 256, 0, stream>>>(Hb, Wk2_b, Wv2_b, k2b, v2b);
    dec_attn_k<<<256, 256, 0, stream>>>(q2, k2b, v2b, attn_d, o2b);
    gemm_g<1><<<12, 256, 0, stream>>>(o2b, Wo2b, nullptr, og2, 256, 1);
    ln3_k<<<768, 256, 0, stream>>>(og2, dec_Qd, z2f, z2b);
    gemm_g<2><<<24, 256, 0, stream>>>(z2b, ff1b, ff1_b, u1b, 256, 2);
    gemm_g<1><<<12, 256, 0, stream>>>(u1b, ff2b, ff2_b, uraw, 512, 1);
    ln5_k<<<768, 256, 0, stream>>>(uraw, z2f, out_w, out_b, coef, y_out);
}